// Round 5
// baseline (426.077 us; speedup 1.0000x reference)
//
#include <hip/hip_runtime.h>
#include <stdint.h>

typedef _Float16 h16;
typedef _Float16 h4v __attribute__((ext_vector_type(4)));
typedef _Float16 h8v __attribute__((ext_vector_type(8)));
typedef float    f4v __attribute__((ext_vector_type(4)));
typedef int      i4v __attribute__((ext_vector_type(4)));

#define NBATCH 4
#define NNODE  2048
#define DM     256
#define NPAD   2063       // NNODE + 15 (SAME pad: 7 low, 8 high)
#define QKELEM 2097152    // 8192*256 elements
#define PARTN  (8192 * 256)
#define SROWS  8          // rows per softmax block (software pipeline depth 2)

// ---------------- async global->LDS (16B per lane, wave-uniform base + lane*16) ----
__device__ __forceinline__ void async16(const void* g, void* l) {
#if __has_builtin(__builtin_amdgcn_global_load_lds)
  __builtin_amdgcn_global_load_lds((__attribute__((address_space(1))) void*)g,
                                   (__attribute__((address_space(3))) void*)l, 16, 0, 0);
#else
  *(f4v*)l = *(const f4v*)g;
#endif
}

#define BARRIER() do { asm volatile("" ::: "memory"); __builtin_amdgcn_s_barrier(); asm volatile("" ::: "memory"); } while (0)
#define MFMA16 __builtin_amdgcn_mfma_f32_16x16x32_f16

// ---------------- shared 128x128xBK32 MFMA GEMM core (round-2 proven version) -----
// Still used by the AV GEMM (its N=256 geometry can't fill the chip at 256^2 tiles).
__device__ __forceinline__ void gemm_tile(
    const h16* Abase, int astride,
    const h16* Bbase, int bstride,
    h16* As, h16* Bs, f4v acc[4][4], int kiters)
{
  const int tid  = threadIdx.x;
  const int lane = tid & 63;
  const int wv   = tid >> 6;
  const int srow = tid >> 2;
  const int sch  = ((tid & 3) ^ ((tid >> 3) & 3)) * 8;   // swizzled source chunk
  const h16* gA0 = Abase + (long)srow * astride + sch;
  const h16* gA1 = Abase + (long)(srow + 64) * astride + sch;
  const h16* gB0 = Bbase + (long)srow * bstride + sch;
  const h16* gB1 = Bbase + (long)(srow + 64) * bstride + sch;
  h16* lA0 = As + tid * 8;
  h16* lA1 = As + 2048 + tid * 8;
  h16* lB0 = Bs + tid * 8;
  h16* lB1 = Bs + 2048 + tid * 8;
  const int swz = ((lane & 15) >> 1) & 3;
  const int qq  = ((lane >> 4) ^ swz) * 8;
  const int amr = ((wv & 1) * 64 + (lane & 15)) * 32 + qq;
  const int bnr = ((wv >> 1) * 64 + (lane & 15)) * 32 + qq;

  for (int kt = 0; kt < kiters; ++kt) {
    const int k0 = kt * 32;
    __syncthreads();
    async16(gA0 + k0, lA0);
    async16(gA1 + k0, lA1);
    async16(gB0 + k0, lB0);
    async16(gB1 + k0, lB1);
    asm volatile("s_waitcnt vmcnt(0)" ::: "memory");
    __syncthreads();
    h8v af[4], bf[4];
#pragma unroll
    for (int i = 0; i < 4; ++i) af[i] = *(const h8v*)(As + amr + i * 512);
#pragma unroll
    for (int j = 0; j < 4; ++j) bf[j] = *(const h8v*)(Bs + bnr + j * 512);
#pragma unroll
    for (int i = 0; i < 4; ++i)
#pragma unroll
      for (int j = 0; j < 4; ++j)
        acc[i][j] = MFMA16(af[i], bf[j], acc[i][j], 0, 0, 0);
  }
}

__device__ __forceinline__ void zero_acc(f4v acc[4][4]) {
#pragma unroll
  for (int i = 0; i < 4; ++i)
#pragma unroll
    for (int j = 0; j < 4; ++j) {
      f4v z = {0.f, 0.f, 0.f, 0.f};
      acc[i][j] = z;
    }
}

// ---------------- 256x256-tile 8-phase counted-vmcnt GEMM pipeline (shared) --------
// T2 (XOR swizzle chunk^=row&7, pre-swizzled source / swizzled read) +
// T3/T4 (4-phase schedule, counted vmcnt, raw s_barrier) + T5 (setprio on MFMA).
// 512 threads = 8 waves (2Mx4N); per wave 128x64 out = acc[8][4]; BK=64.
// LDS per operand = 2 slots x [256 rows][64 k] = 64 KB (128 KB total).
// Schedule per K-tile (verified in R0's conv kernel):
//   ph1 read a[0-3]+bL, stage A1(kt+1) | ph2 read bR, stage B0(kt+1)
//   ph3 read a[4-7],    stage B1(kt+1) | ph4 re-read bL, stage A0(kt+2) + vmcnt(2)
// vmcnt never drains to 0 in the main loop (last 2 iters excepted).
template<int ASTRIDE, int BSTRIDE>
__device__ __forceinline__ void gemm256_pipe(
    const h16* __restrict__ Abase, const h16* __restrict__ Bbase,
    h16* As, h16* Bs, f4v (&acc)[8][4], const int kiters)
{
  const int tid  = threadIdx.x;
  const int lane = tid & 63, wv = tid >> 6;

  const int rh = tid >> 3;
  const int cs = (((tid & 7) ^ ((tid >> 3) & 7)) << 3);
  const h16* AgT = Abase + (long)rh * ASTRIDE + cs;
  const h16* BgT = Bbase + (long)rh * BSTRIDE + cs;
  h16* lA = As + tid * 8;
  h16* lB = Bs + tid * 8;

  auto stageA = [&](int kt, int half) {
    h16* d = lA + ((kt & 1) << 14) + (half << 13);
    const h16* g = AgT + (long)half * 128 * ASTRIDE + kt * 64;
    async16(g, d);
    async16(g + 64 * ASTRIDE, d + 4096);
  };
  auto stageB = [&](int kt, int half) {
    h16* d = lB + ((kt & 1) << 14) + (half << 13);
    const h16* g = BgT + (long)half * 128 * BSTRIDE + kt * 64;
    async16(g, d);
    async16(g + 64 * BSTRIDE, d + 4096);
  };

  const int wr = wv >> 2, wc = wv & 3;
  const int e0 = (((lane >> 4) ^ (lane & 7)) << 3);
  const int e1 = e0 ^ 32;
  const h16* pA0 = As + (wr * 128 + (lane & 15)) * 64 + e0;
  const h16* pA1 = pA0 + (e1 - e0);
  const h16* pB0 = Bs + (wc * 64 + (lane & 15)) * 64 + e0;
  const h16* pB1 = pB0 + (e1 - e0);

#pragma unroll
  for (int i = 0; i < 8; ++i)
#pragma unroll
    for (int j = 0; j < 4; ++j) { f4v z = {0.f, 0.f, 0.f, 0.f}; acc[i][j] = z; }

  // prologue: kt0 fully + A0(kt1); leave A0(kt1)'s 2 loads in flight.
  stageA(0, 0); stageA(0, 1); stageB(0, 0); stageB(0, 1); stageA(1, 0);
  asm volatile("s_waitcnt vmcnt(2)" ::: "memory");
  BARRIER();

#pragma unroll 1
  for (int kt = 0; kt < kiters; ++kt) {
    const int sb = (kt & 1) << 14;
    h8v ar[4][2], bL[2][2], bR[2][2];
    // ---- phase 1: TL -> acc[0-3][0-1] ----
#pragma unroll
    for (int i = 0; i < 4; ++i) {
      ar[i][0] = *(const h8v*)(pA0 + sb + i * 1024);
      ar[i][1] = *(const h8v*)(pA1 + sb + i * 1024);
    }
#pragma unroll
    for (int j = 0; j < 2; ++j) {
      bL[j][0] = *(const h8v*)(pB0 + sb + j * 1024);
      bL[j][1] = *(const h8v*)(pB1 + sb + j * 1024);
    }
    if (kt < kiters - 1) stageA(kt + 1, 1);
    BARRIER();
    __builtin_amdgcn_s_setprio(1);
#pragma unroll
    for (int i = 0; i < 4; ++i)
#pragma unroll
      for (int j = 0; j < 2; ++j) {
        acc[i][j] = MFMA16(ar[i][0], bL[j][0], acc[i][j], 0, 0, 0);
        acc[i][j] = MFMA16(ar[i][1], bL[j][1], acc[i][j], 0, 0, 0);
      }
    __builtin_amdgcn_s_setprio(0);
    BARRIER();
    // ---- phase 2: TR -> acc[0-3][2-3] ----
#pragma unroll
    for (int j = 0; j < 2; ++j) {
      bR[j][0] = *(const h8v*)(pB0 + sb + (j + 2) * 1024);
      bR[j][1] = *(const h8v*)(pB1 + sb + (j + 2) * 1024);
    }
    if (kt < kiters - 1) stageB(kt + 1, 0);
    BARRIER();
    __builtin_amdgcn_s_setprio(1);
#pragma unroll
    for (int i = 0; i < 4; ++i)
#pragma unroll
      for (int j = 0; j < 2; ++j) {
        acc[i][j + 2] = MFMA16(ar[i][0], bR[j][0], acc[i][j + 2], 0, 0, 0);
        acc[i][j + 2] = MFMA16(ar[i][1], bR[j][1], acc[i][j + 2], 0, 0, 0);
      }
    __builtin_amdgcn_s_setprio(0);
    BARRIER();
    // ---- phase 3: BR -> acc[4-7][2-3] (ar <- rows 64-127) ----
#pragma unroll
    for (int i = 0; i < 4; ++i) {
      ar[i][0] = *(const h8v*)(pA0 + sb + (i + 4) * 1024);
      ar[i][1] = *(const h8v*)(pA1 + sb + (i + 4) * 1024);
    }
    if (kt < kiters - 1) stageB(kt + 1, 1);
    BARRIER();
    __builtin_amdgcn_s_setprio(1);
#pragma unroll
    for (int i = 0; i < 4; ++i)
#pragma unroll
      for (int j = 0; j < 2; ++j) {
        acc[i + 4][j + 2] = MFMA16(ar[i][0], bR[j][0], acc[i + 4][j + 2], 0, 0, 0);
        acc[i + 4][j + 2] = MFMA16(ar[i][1], bR[j][1], acc[i + 4][j + 2], 0, 0, 0);
      }
    __builtin_amdgcn_s_setprio(0);
    BARRIER();
    // ---- phase 4: BL -> acc[4-7][0-1] (re-read bL) ----
#pragma unroll
    for (int j = 0; j < 2; ++j) {
      bL[j][0] = *(const h8v*)(pB0 + sb + j * 1024);
      bL[j][1] = *(const h8v*)(pB1 + sb + j * 1024);
    }
    if (kt < kiters - 2) {
      stageA(kt + 2, 0);
      asm volatile("s_waitcnt vmcnt(2)" ::: "memory");
    } else if (kt == kiters - 2) {
      asm volatile("s_waitcnt vmcnt(0)" ::: "memory");
    }
    BARRIER();
    __builtin_amdgcn_s_setprio(1);
#pragma unroll
    for (int i = 0; i < 4; ++i)
#pragma unroll
      for (int j = 0; j < 2; ++j) {
        acc[i + 4][j] = MFMA16(ar[i][0], bL[j][0], acc[i + 4][j], 0, 0, 0);
        acc[i + 4][j] = MFMA16(ar[i][1], bL[j][1], acc[i + 4][j], 0, 0, 0);
      }
    __builtin_amdgcn_s_setprio(0);
    BARRIER();
  }
}

// ---------------- merged prep kernel (src pad + conv-W transpose + lin-W cast) ----
#define NSRC_BLK 8252   // NBATCH*NPAD*DM/256
__global__ __launch_bounds__(256) void prep_all_kernel(
    const float* __restrict__ src,
    const float* __restrict__ Wq, const float* __restrict__ Wk, const float* __restrict__ Wv,
    const float* __restrict__ W1, const float* __restrict__ W2, const float* __restrict__ W3,
    h16* __restrict__ Xpad, h16* __restrict__ Wt, h16* __restrict__ Wl)
{
  __shared__ float plds[16][257];
  const int bi = blockIdx.x, tid = threadIdx.x;
  if (bi < NSRC_BLK) {
    int idx = bi * 256 + tid;
    int c = idx & 255;
    int row = idx >> 8;
    int b = row / NPAD;
    int n = row - b * NPAD;
    float v = 0.f;
    int ns = n - 7;
    if (ns >= 0 && ns < NNODE) v = src[((long)b * NNODE + ns) * DM + c];
    Xpad[idx] = (h16)v;
  } else if (bi < NSRC_BLK + 768) {
    // coalesced read of W[o][c][t], LDS transpose, coalesced write Wt[w][o][t][c]
    const int q = bi - NSRC_BLK;
    const int w = q >> 8, o = q & 255;
    const float* W = (w == 0) ? Wq : (w == 1) ? Wk : Wv;
    const float* base = W + (long)o * 4096;
    f4v r0 = *(const f4v*)(base + tid * 16);
    f4v r1 = *(const f4v*)(base + tid * 16 + 4);
    f4v r2 = *(const f4v*)(base + tid * 16 + 8);
    f4v r3 = *(const f4v*)(base + tid * 16 + 12);
#pragma unroll
    for (int k = 0; k < 4; ++k) {
      plds[k][tid] = r0[k]; plds[4 + k][tid] = r1[k];
      plds[8 + k][tid] = r2[k]; plds[12 + k][tid] = r3[k];
    }
    __syncthreads();
    const int t = tid >> 4, c0 = (tid & 15) * 16;
    h16* out = Wt + ((long)(w * 256 + o)) * 4096 + t * 256 + c0;
    h8v o0, o1;
#pragma unroll
    for (int k = 0; k < 8; ++k) { o0[k] = (h16)plds[t][c0 + k]; o1[k] = (h16)plds[t][c0 + 8 + k]; }
    *(h8v*)out = o0;
    *(h8v*)(out + 8) = o1;
  } else {
    int idx = (bi - NSRC_BLK - 768) * 256 + tid;   // over 3*65536
    int w = idx >> 16;
    int rem = idx & 65535;
    const float* W = (w == 0) ? W1 : (w == 1) ? W2 : W3;
    Wl[idx] = (h16)W[rem];
  }
}

// ---------------- conv GEMM: 256x256 tile, 8-phase pipeline, split-K x2 -----------
// Grid (32 Mtiles, 3 weights, 2 ksplits) = 192 blocks x 512 thr.
__global__ __launch_bounds__(512) void conv_gemm256_kernel(
    const h16* __restrict__ Xpad, const h16* __restrict__ Wt,
    h16* __restrict__ Qp, h16* __restrict__ Kp, h16* __restrict__ Vp)
{
  __shared__ __align__(16) h16 As[32768];   // [2 slots][256 rows][64 k]
  __shared__ __align__(16) h16 Bs[32768];
  const int lane = threadIdx.x & 63, wv = threadIdx.x >> 6;
  const int mt = blockIdx.x, w = blockIdx.y, ks = blockIdx.z;
  const int m0 = mt * 256;
  const int b  = m0 >> 11, n0 = m0 & 2047;

  const h16* Abase = Xpad + ((long)(b * NPAD + n0) << 8) + ((long)ks << 11);
  const h16* Bbase = Wt + ((long)w << 20) + ((long)ks << 11);

  f4v acc[8][4];
  gemm256_pipe<256, 4096>(Abase, Bbase, As, Bs, acc, 32);

  // epilogue: all outputs (incl. V) as [ks][m][c] f16 partials.
  h16* dst = ((w == 0) ? Qp : (w == 1) ? Kp : Vp) + (long)ks * QKELEM;
  const int wr = wv >> 2, wc = wv & 3;
  const int rb = (lane >> 4) * 4;
  const int cb = wc * 64 + (lane & 15);
  const int mrow0 = m0 + wr * 128;
#pragma unroll
  for (int i = 0; i < 8; ++i)
#pragma unroll
    for (int j = 0; j < 4; ++j) {
      const int gc = cb + j * 16;
#pragma unroll
      for (int e = 0; e < 4; ++e) {
        const int gr = mrow0 + i * 16 + rb + e;
        dst[(long)gr * 256 + gc] = (h16)acc[i][j][e];
      }
    }
}

// ---------------- conv reduce: sum 2 partials + bias -> Q,K [m][c]; V -> Vt[b][d][m]
// V path does a 64x64 LDS transpose (f32 [64][65], 2-way max bank aliasing) so both
// the global read ([m][c]) and write ([b][d][m]) are h8v-coalesced.
__global__ __launch_bounds__(256) void conv_reduce_kernel(
    const h16* __restrict__ Qp, const h16* __restrict__ Kp, const h16* __restrict__ Vp,
    const float* __restrict__ bq, const float* __restrict__ bk, const float* __restrict__ bv,
    h16* __restrict__ Qb, h16* __restrict__ Kb, h16* __restrict__ Vt)
{
  __shared__ float T[64][65];
  const int bi = blockIdx.x, tid = threadIdx.x;
  if (bi < 2048) {
    const long gid = (long)bi * 256 + tid;
    const int which = gid >= (QKELEM / 8);
    const long e = (gid - (long)which * (QKELEM / 8)) * 8;
    const h16* P = which ? Kp : Qp;
    const float* bias = which ? bk : bq;
    h8v p0 = *(const h8v*)(P + e);
    h8v p1 = *(const h8v*)(P + QKELEM + e);
    const int c0 = (int)(e & 255);
    h8v o;
#pragma unroll
    for (int k = 0; k < 8; ++k) o[k] = (h16)((float)p0[k] + (float)p1[k] + bias[c0 + k]);
    *(h8v*)((which ? Kb : Qb) + e) = o;
  } else {
    const int q = bi - 2048;                 // 0..511: (8192/64) m-tiles x (256/64) c-tiles
    const int mt = q >> 2, ct = q & 3;
    const int m0 = mt * 64, c0 = ct * 64;
    const int b = m0 >> 11, n0 = m0 & 2047;
    const int rr = tid >> 3, cc = (tid & 7) * 8;
#pragma unroll
    for (int p = 0; p < 2; ++p) {
      const int r = p * 32 + rr;
      const long so = (long)(m0 + r) * 256 + c0 + cc;
      h8v p0 = *(const h8v*)(Vp + so);
      h8v p1 = *(const h8v*)(Vp + QKELEM + so);
#pragma unroll
      for (int e = 0; e < 8; ++e) T[r][cc + e] = (float)p0[e] + (float)p1[e];
    }
    __syncthreads();
#pragma unroll
    for (int p = 0; p < 2; ++p) {
      const int d = p * 32 + rr;
      const float bias_v = bv[c0 + d];
      h8v o;
#pragma unroll
      for (int e = 0; e < 8; ++e) o[e] = (h16)(T[cc + e][d] + bias_v);
      *(h8v*)(Vt + ((long)(b * 256 + c0 + d)) * 2048 + n0 + cc) = o;
    }
  }
}

// ---------------- scores GEMM: 256x256-tile 8-phase, S[b][n][m] f16 ---------------
// Grid (8 ntiles, 8 mtiles, 4 batch) = 256 blocks x 512 thr; K=256 -> kiters=4.
__global__ __launch_bounds__(512) void scores_gemm256_kernel(
    const h16* __restrict__ Q, const h16* __restrict__ Km, h16* __restrict__ Sh)
{
  __shared__ __align__(16) h16 As[32768];
  __shared__ __align__(16) h16 Bs[32768];
  const int lane = threadIdx.x & 63, wv = threadIdx.x >> 6;
  const int nt = blockIdx.x, mt = blockIdx.y, b = blockIdx.z;

  const h16* Abase = Q + ((long)b * NNODE + nt * 256) * 256;
  const h16* Bbase = Km + ((long)b * NNODE + mt * 256) * 256;

  f4v acc[8][4];
  gemm256_pipe<256, 256>(Abase, Bbase, As, Bs, acc, 4);

  const int wr = wv >> 2, wc = wv & 3;
  const int rb = (lane >> 4) * 4;
  const int cb = wc * 64 + (lane & 15);
  h16* Srow = Sh + (long)b * NNODE * NNODE;
  const int row0 = nt * 256 + wr * 128;
  const int col0 = mt * 256;
#pragma unroll
  for (int i = 0; i < 8; ++i) {
#pragma unroll
    for (int e = 0; e < 4; ++e) {
      const long row = row0 + i * 16 + rb + e;
#pragma unroll
      for (int j = 0; j < 4; ++j) {
        const int col = col0 + cb + j * 16;
        Srow[row * 2048 + col] = (h16)(acc[i][j][e] * 0.0625f);
      }
    }
  }
}

// ---------------- fused mask + softmax + x_lst_new + attn(f16, in-place) ----------
// R4 dense mapping + software pipeline: each block owns SROWS consecutive rows;
// row r+1's 8 loads (incl. x_lst, hoisted) issue BEFORE row r's reductions, so the
// memory pipe never drains during the barrier/reduce phase (MLP fix for the 2.7 TB/s
// plateau). Named cur/next register rotation, #pragma unroll 1 (no runtime-indexed
// arrays -> no scratch).
__global__ __launch_bounds__(256) void softmax_kernel(
    h16* __restrict__ Sh, const float* __restrict__ dis, const int* __restrict__ adj,
    const float* __restrict__ x_lst, float* __restrict__ out_x)
{
  const int tid = threadIdx.x, lane = tid & 63, wv = tid >> 6;
  const int j0 = tid * 4;
  __shared__ float wmax[4], wsum[4];

  long ro = (long)blockIdx.x * SROWS * 2048;

  h4v sv0 = *(const h4v*)(Sh + ro + j0);
  h4v sv1 = *(const h4v*)(Sh + ro + 1024 + j0);
  f4v d0  = *(const f4v*)(dis + ro + j0);
  f4v d1  = *(const f4v*)(dis + ro + 1024 + j0);
  i4v a0  = *(const i4v*)(adj + ro + j0);
  i4v a1  = *(const i4v*)(adj + ro + 1024 + j0);
  f4v x0  = *(const f4v*)(x_lst + ro + j0);
  f4v x1  = *(const f4v*)(x_lst + ro + 1024 + j0);

#pragma unroll 1
  for (int r = 0; r < SROWS; ++r) {
    const long nro = ro + 2048;
    h4v nsv0, nsv1; f4v nd0, nd1, nx0, nx1; i4v na0, na1;
    if (r + 1 < SROWS) {           // prefetch next row before this row's reductions
      nsv0 = *(const h4v*)(Sh + nro + j0);
      nsv1 = *(const h4v*)(Sh + nro + 1024 + j0);
      nd0  = *(const f4v*)(dis + nro + j0);
      nd1  = *(const f4v*)(dis + nro + 1024 + j0);
      na0  = *(const i4v*)(adj + nro + j0);
      na1  = *(const i4v*)(adj + nro + 1024 + j0);
      nx0  = *(const f4v*)(x_lst + nro + j0);
      nx1  = *(const f4v*)(x_lst + nro + 1024 + j0);
    }

    float s[8];
#pragma unroll
    for (int k = 0; k < 4; ++k) s[k]     = (a0[k] > 0) ? ((float)sv0[k] - d0[k]) : -1e9f;
#pragma unroll
    for (int k = 0; k < 4; ++k) s[k + 4] = (a1[k] > 0) ? ((float)sv1[k] - d1[k]) : -1e9f;

    float m = s[0];
#pragma unroll
    for (int k = 1; k < 8; ++k) m = fmaxf(m, s[k]);
#pragma unroll
    for (int off = 32; off > 0; off >>= 1) m = fmaxf(m, __shfl_xor(m, off, 64));
    if (lane == 0) wmax[wv] = m;
    __syncthreads();
    m = fmaxf(fmaxf(wmax[0], wmax[1]), fmaxf(wmax[2], wmax[3]));

    float p[8], ls = 0.f;
#pragma unroll
    for (int k = 0; k < 8; ++k) { p[k] = __expf(s[k] - m); ls += p[k]; }
#pragma unroll
    for (int off = 32; off > 0; off >>= 1) ls += __shfl_xor(ls, off, 64);
    if (lane == 0) wsum[wv] = ls;
    __syncthreads();
    const float inv = 1.0f / (wsum[0] + wsum[1] + wsum[2] + wsum[3]);

    f4v o0, o1;
    h4v pv0, pv1;
#pragma unroll
    for (int k = 0; k < 4; ++k) {
      const float pa = p[k] * inv, pb = p[k + 4] * inv;
      o0[k] = x0[k] + pa; o1[k] = x1[k] + pb;
      pv0[k] = (h16)pa; pv1[k] = (h16)pb;
    }
    *(f4v*)(out_x + ro + j0) = o0;
    *(f4v*)(out_x + ro + 1024 + j0) = o1;
    *(h4v*)(Sh + ro + j0) = pv0;
    *(h4v*)(Sh + ro + 1024 + j0) = pv1;

    // rotate (garbage on last iteration is never used)
    sv0 = nsv0; sv1 = nsv1; d0 = nd0; d1 = nd1;
    a0 = na0; a1 = na1; x0 = nx0; x1 = nx1;
    ro = nro;
  }
}

// ---------------- AV GEMM (split-K x2): X1p[ks][m][d] f16 partials ----------------
__global__ __launch_bounds__(256) void av_gemm_kernel(
    const h16* __restrict__ Attn, const h16* __restrict__ Vt, h16* __restrict__ X1p)
{
  __shared__ __align__(16) h16 As[4096];
  __shared__ __align__(16) h16 Bs[4096];
  const int nt = blockIdx.x, b = blockIdx.z;
  const int ct = blockIdx.y & 1, ks = blockIdx.y >> 1;
  const h16* Abase = Attn + ((long)b * NNODE + nt * 128) * 2048 + ks * 1024;
  const h16* Bbase = Vt + ((long)b * 256 + ct * 128) * 2048 + ks * 1024;
  f4v acc[4][4];
  zero_acc(acc);
  gemm_tile(Abase, 2048, Bbase, 2048, As, Bs, acc, 32);

  const int lane = threadIdx.x & 63, wv = threadIdx.x >> 6;
  const int rbase = (wv & 1) * 64 + (lane >> 4) * 4;
  const int cbase = (wv >> 1) * 64 + (lane & 15);
  h16* dst = X1p + (long)ks * PARTN;
#pragma unroll
  for (int i = 0; i < 4; ++i) {
#pragma unroll
    for (int e = 0; e < 4; ++e) {
      const long row = (long)b * NNODE + nt * 128 + rbase + i * 16 + e;
#pragma unroll
      for (int j = 0; j < 4; ++j) {
        const int col = ct * 128 + cbase + j * 16;
        dst[row * 256 + col] = (h16)acc[i][j][e];
      }
    }
  }
}

// ---------------- fused residual + partial-sum + LayerNorm1 -----------------------
__device__ __forceinline__ float wred_sum(float v) {
#pragma unroll
  for (int off = 32; off > 0; off >>= 1) v += __shfl_xor(v, off, 64);
  return v;
}

__global__ __launch_bounds__(256) void ln1_kernel(
    const float* __restrict__ X, const h16* __restrict__ Y, const h16* __restrict__ Y2,
    const float* __restrict__ g, const float* __restrict__ bb,
    float* __restrict__ outF, h16* __restrict__ outH)
{
  const int wv = threadIdx.x >> 6, lane = threadIdx.x & 63;
  const long r = (long)blockIdx.x * 4 + wv;
  const long off = r * 256 + lane * 4;
  f4v x = *(const f4v*)(X + off);
  h4v y = *(const h4v*)(Y + off);
  h4v y2 = *(const h4v*)(Y2 + off);
  float v[4];
  float sum = 0.f, sq = 0.f;
#pragma unroll
  for (int k = 0; k < 4; ++k) {
    v[k] = x[k] + (float)y[k] + (float)y2[k];
    sum += v[k]; sq += v[k] * v[k];
  }
  sum = wred_sum(sum);
  sq  = wred_sum(sq);
  const float mu = sum * (1.0f / 256.0f);
  const float var = sq * (1.0f / 256.0f) - mu * mu;
  const float rs = rsqrtf(var + 1e-5f);
  f4v gg = *(const f4v*)(g + lane * 4);
  f4v be = *(const f4v*)(bb + lane * 4);
  f4v o;
#pragma unroll
  for (int k = 0; k < 4; ++k) o[k] = (v[k] - mu) * rs * gg[k] + be[k];
  *(f4v*)(outF + off) = o;
  h4v hv;
#pragma unroll
  for (int k = 0; k < 4; ++k) hv[k] = (h16)o[k];
  *(h4v*)(outH + off) = hv;
}

// ---------------- fused 3-layer MLP + residual + LayerNorm2 -----------------------
__global__ __launch_bounds__(256) void mlp_fused_kernel(
    const h16* __restrict__ H16, const float* __restrict__ Hf,
    const h16* __restrict__ Wl,
    const float* __restrict__ b1, const float* __restrict__ b2, const float* __restrict__ b3,
    const float* __restrict__ g2, const float* __restrict__ be2,
    float* __restrict__ out_h)
{
  __shared__ h16 Xa[32][264];
  __shared__ h16 Xb[32][264];
  __shared__ __align__(16) h16 Bs[8192];      // 256 out-cols x 32 k
  const int tid = threadIdx.x, lane = tid & 63, wv = tid >> 6;
  const int m0 = blockIdx.x * 32;

  { // load LN1 output rows into Xa (coalesced global, padded LDS writes)
    const int r = tid >> 3, cq = (tid & 7) * 32;
    const h16* s = H16 + (long)(m0 + r) * 256 + cq;
#pragma unroll
    for (int k = 0; k < 4; ++k)
      *(h8v*)&Xa[r][cq + k * 8] = *(const h8v*)(s + k * 8);
  }

  const int srow = tid >> 2;
  const int sch  = ((tid & 3) ^ ((tid >> 3) & 3)) * 8;
  h16* lB = Bs + tid * 8;
  const int quad = lane >> 4;
  const float* biases[3] = {b1, b2, b3};

  for (int layer = 0; layer < 3; ++layer) {
    const h16* W = Wl + layer * 65536;
    const h16 (*Xi)[264] = (layer == 1) ? (const h16(*)[264])Xb : (const h16(*)[264])Xa;
    h16 (*Xo)[264] = (layer == 1) ? Xa : Xb;
    f4v acc[2][4];
#pragma unroll
    for (int i = 0; i < 2; ++i)
#pragma unroll
      for (int j = 0; j < 4; ++j) { f4v z = {0.f,0.f,0.f,0.f}; acc[i][j] = z; }

    for (int kt = 0; kt < 8; ++kt) {
      __syncthreads();
      const h16* gB = W + (long)srow * 256 + kt * 32 + sch;
      async16(gB, lB);
      async16(gB + 64 * 256, lB + 64 * 32);
      async16(gB + 128 * 256, lB + 128 * 32);
      async16(gB + 192 * 256, lB + 192 * 32);
      asm volatile("s_waitcnt vmcnt(0)" ::: "memory");
      __syncthreads();
      h8v af[2], bf[4];
#pragma unroll
      for (int i = 0; i < 2; ++i)
        af[i] = *(const h8v*)&Xi[i * 16 + (lane & 15)][kt * 32 + quad * 8];
#pragma unroll
      for (int j = 0; j < 4; ++j) {
        const int n = wv * 64 + j * 16 + (lane & 15);
        const int q = (quad ^ ((n >> 1) & 3)) * 8;
        bf[j] = *(const h8v*)(Bs + n * 32 + q);
      }
#pragma unroll
      for (int i = 0; i < 2; ++i)
#pragma unroll
        for (int j = 0; j < 4; ++j)
          acc[i][j] = MFMA16(af[i], bf[j], acc[i][j], 0, 0, 0);
    }
    // epilogue: bias (+leaky for layers 0/1), write to Xo (other buffer -> no race)
    const int rb = quad * 4;
    const int cb = wv * 64 + (lane & 15);
    const float* bias = biases[layer];
    const bool leaky = (layer < 2);
#pragma unroll
    for (int j = 0; j < 4; ++j) {
      const int col = cb + j * 16;
      const float bv = bias[col];
#pragma unroll
      for (int i = 0; i < 2; ++i)
#pragma unroll
        for (int e = 0; e < 4; ++e) {
          float v = acc[i][j][e] + bv;
          if (leaky) v = (v >= 0.f) ? v : 0.01f * v;
          Xo[i * 16 + rb + e][col] = (h16)v;
        }
    }
  }
  __syncthreads();

  // LN2: rows in Xb (layer-3 out), residual Hf, write out_h. 8 threads/row.
  const int r = tid >> 3, c0 = (tid & 7) * 32;
  const float* hrow = Hf + (long)(m0 + r) * 256 + c0;
  float v[32];
  float s = 0.f, sq = 0.f;
#pragma unroll
  for (int k8 = 0; k8 < 8; ++k8) {
    f4v h4 = *(const f4v*)(hrow + k8 * 4);
#pragma unroll
    for (int e = 0; e < 4; ++e) {
      float t = (float)Xb[r][c0 + k8 * 4 + e] + h4[e];
      v[k8 * 4 + e] = t; s += t; sq += t * t;
    }
  }
#pragma unroll
  for (int off = 1; off < 8; off <<= 1) { s += __shfl_xor(s, off, 64); sq += __shfl_xor(sq, off, 64); }
  const float mu = s * (1.0f / 256.0f);
  const float var = sq * (1.0f / 256.0f) - mu * mu;
  const float rs = rsqrtf(var + 1e-5f);
  float* orow = out_h + (long)(m0 + r) * 256 + c0;
#pragma unroll
  for (int k8 = 0; k8 < 8; ++k8) {
    f4v gg = *(const f4v*)(g2 + c0 + k8 * 4);
    f4v be = *(const f4v*)(be2 + c0 + k8 * 4);
    f4v o;
#pragma unroll
    for (int e = 0; e < 4; ++e) o[e] = (v[k8 * 4 + e] - mu) * rs * gg[e] + be[e];
    *(f4v*)(orow + k8 * 4) = o;
  }
}

// ---------------- launch ----------------------------------------------------------
extern "C" void kernel_launch(void* const* d_in, const int* in_sizes, int n_in,
                              void* d_out, int out_size, void* d_ws, size_t ws_size,
                              hipStream_t stream)
{
  const float* src  = (const float*)d_in[0];
  const float* xlst = (const float*)d_in[1];
  const int*   adj  = (const int*)d_in[2];
  const float* dis  = (const float*)d_in[3];
  const float* Wq   = (const float*)d_in[4];
  const float* bq   = (const float*)d_in[5];
  const float* Wk   = (const float*)d_in[6];
  const float* bk   = (const float*)d_in[7];
  const float* Wv   = (const float*)d_in[8];
  const float* bvp  = (const float*)d_in[9];
  const float* W1   = (const float*)d_in[10];
  const float* b1   = (const float*)d_in[11];
  const float* W2   = (const float*)d_in[12];
  const float* b2   = (const float*)d_in[13];
  const float* W3   = (const float*)d_in[14];
  const float* b3   = (const float*)d_in[15];
  const float* g1   = (const float*)d_in[16];
  const float* be1  = (const float*)d_in[17];
  const float* g2   = (const float*)d_in[18];
  const float* be2  = (const float*)d_in[19];
  (void)in_sizes; (void)n_in; (void)out_size; (void)ws_size;

  char* ws = (char*)d_ws;
  size_t off = 0;
  auto alloc = [&](size_t bytes) -> void* {
    void* p = ws + off;
    off += (bytes + 1023) & ~(size_t)1023;
    return p;
  };
  h16*   Xpad = (h16*)  alloc((size_t)NBATCH * NPAD * DM * 2);       // 4.2 MB
  h16*   Wt   = (h16*)  alloc((size_t)3 * 256 * 4096 * 2);           // 6.3 MB
  h16*   Wl   = (h16*)  alloc((size_t)3 * 256 * 256 * 2);            // 0.4 MB
  h16*   Qb   = (h16*)  alloc((size_t)QKELEM * 2);                   // 4 MB
  h16*   Kb   = (h16*)  alloc((size_t)QKELEM * 2);                   // 4 MB
  h16*   Vt   = (h16*)  alloc((size_t)QKELEM * 2);                   // 4 MB
  // union region R: conv partials (25 MB, dead after reduce) overlap Sh/X1p.
  char*  R    = (char*) alloc((size_t)66000 * 1024);                 // ~64.5 MB
  h16*   Qp   = (h16*)R;                                   // [2][m][c]  8.4 MB
  h16*   Kp   = (h16*)(R + (size_t)2 * QKELEM * 2);        // [2][m][c]  8.4 MB
  h16*   Vp   = (h16*)(R + (size_t)4 * QKELEM * 2);        // [2][m][c]  8.4 MB
  h16*   Sh   = (h16*)R;                                   // 32 MB (over dead Qp/Kp/Vp)
  h16*   X1p  = (h16*)(R + (size_t)8 * QKELEM * 2);        // 8.4 MB (just past Sh)
  float* H    = (float*)(R + (size_t)12 * QKELEM * 2);     // 8 MB
  h16*   H16  = (h16*)((char*)H + (size_t)PARTN * 4);      // 4 MB

  float* out_h = (float*)d_out;                        // [B,N,d]
  float* out_x = out_h + (size_t)NBATCH * NNODE * DM;  // [B,N,N]

  prep_all_kernel<<<NSRC_BLK + 768 + 768, 256, 0, stream>>>(
      src, Wq, Wk, Wv, W1, W2, W3, Xpad, Wt, Wl);
  conv_gemm256_kernel<<<dim3(32, 3, 2), 512, 0, stream>>>(Xpad, Wt, Qp, Kp, Vp);
  conv_reduce_kernel<<<2048 + 512, 256, 0, stream>>>(
      Qp, Kp, Vp, bq, bk, bvp, Qb, Kb, Vt);
  scores_gemm256_kernel<<<dim3(8, 8, 4), 512, 0, stream>>>(Qb, Kb, Sh);
  softmax_kernel<<<(NBATCH * NNODE) / SROWS, 256, 0, stream>>>(Sh, dis, adj, xlst, out_x);
  av_gemm_kernel<<<dim3(16, 4, 4), 256, 0, stream>>>(Sh, Vt, X1p);
  ln1_kernel<<<(NBATCH * NNODE) / 4, 256, 0, stream>>>(src, X1p, X1p + PARTN, g1, be1, H, H16);
  mlp_fused_kernel<<<NBATCH * NNODE / 32, 256, 0, stream>>>(
      H16, H, Wl, b1, b2, b3, g2, be2, out_h);
}

// Round 6
// 421.397 us; speedup vs baseline: 1.0111x; 1.0111x over previous
//
#include <hip/hip_runtime.h>
#include <stdint.h>

typedef _Float16 h16;
typedef _Float16 h4v __attribute__((ext_vector_type(4)));
typedef _Float16 h8v __attribute__((ext_vector_type(8)));
typedef float    f4v __attribute__((ext_vector_type(4)));
typedef int      i4v __attribute__((ext_vector_type(4)));

#define NBATCH 4
#define NNODE  2048
#define DM     256
#define NPAD   2063       // NNODE + 15 (SAME pad: 7 low, 8 high)
#define QKELEM 2097152    // 8192*256 elements
#define PARTN  (8192 * 256)

// ---------------- async global->LDS (16B per lane, wave-uniform base + lane*16) ----
__device__ __forceinline__ void async16(const void* g, void* l) {
#if __has_builtin(__builtin_amdgcn_global_load_lds)
  __builtin_amdgcn_global_load_lds((__attribute__((address_space(1))) void*)g,
                                   (__attribute__((address_space(3))) void*)l, 16, 0, 0);
#else
  *(f4v*)l = *(const f4v*)g;
#endif
}

#define BARRIER() do { asm volatile("" ::: "memory"); __builtin_amdgcn_s_barrier(); asm volatile("" ::: "memory"); } while (0)
#define MFMA16 __builtin_amdgcn_mfma_f32_16x16x32_f16

// ---------------- shared 128x128xBK32 MFMA GEMM core (round-2 proven version) -----
// Used by scores (reverted from 256^2: kiters=4 was prologue-dominated at 1 blk/CU)
// and by the AV GEMM. ~3 blocks/CU co-residency hides epilogue memory tails.
__device__ __forceinline__ void gemm_tile(
    const h16* Abase, int astride,
    const h16* Bbase, int bstride,
    h16* As, h16* Bs, f4v acc[4][4], int kiters)
{
  const int tid  = threadIdx.x;
  const int lane = tid & 63;
  const int wv   = tid >> 6;
  const int srow = tid >> 2;
  const int sch  = ((tid & 3) ^ ((tid >> 3) & 3)) * 8;   // swizzled source chunk
  const h16* gA0 = Abase + (long)srow * astride + sch;
  const h16* gA1 = Abase + (long)(srow + 64) * astride + sch;
  const h16* gB0 = Bbase + (long)srow * bstride + sch;
  const h16* gB1 = Bbase + (long)(srow + 64) * bstride + sch;
  h16* lA0 = As + tid * 8;
  h16* lA1 = As + 2048 + tid * 8;
  h16* lB0 = Bs + tid * 8;
  h16* lB1 = Bs + 2048 + tid * 8;
  const int swz = ((lane & 15) >> 1) & 3;
  const int qq  = ((lane >> 4) ^ swz) * 8;
  const int amr = ((wv & 1) * 64 + (lane & 15)) * 32 + qq;
  const int bnr = ((wv >> 1) * 64 + (lane & 15)) * 32 + qq;

  for (int kt = 0; kt < kiters; ++kt) {
    const int k0 = kt * 32;
    __syncthreads();
    async16(gA0 + k0, lA0);
    async16(gA1 + k0, lA1);
    async16(gB0 + k0, lB0);
    async16(gB1 + k0, lB1);
    asm volatile("s_waitcnt vmcnt(0)" ::: "memory");
    __syncthreads();
    h8v af[4], bf[4];
#pragma unroll
    for (int i = 0; i < 4; ++i) af[i] = *(const h8v*)(As + amr + i * 512);
#pragma unroll
    for (int j = 0; j < 4; ++j) bf[j] = *(const h8v*)(Bs + bnr + j * 512);
#pragma unroll
    for (int i = 0; i < 4; ++i)
#pragma unroll
      for (int j = 0; j < 4; ++j)
        acc[i][j] = MFMA16(af[i], bf[j], acc[i][j], 0, 0, 0);
  }
}

__device__ __forceinline__ void zero_acc(f4v acc[4][4]) {
#pragma unroll
  for (int i = 0; i < 4; ++i)
#pragma unroll
    for (int j = 0; j < 4; ++j) {
      f4v z = {0.f, 0.f, 0.f, 0.f};
      acc[i][j] = z;
    }
}

// ---------------- 256x256-tile 8-phase counted-vmcnt GEMM pipeline (conv only) -----
// T2 (XOR swizzle chunk^=row&7) + T3/T4 (phase schedule, counted vmcnt, raw
// s_barrier) + T5 (setprio). Proven on conv (kiters=32); NOT used for short-K GEMMs.
template<int ASTRIDE, int BSTRIDE>
__device__ __forceinline__ void gemm256_pipe(
    const h16* __restrict__ Abase, const h16* __restrict__ Bbase,
    h16* As, h16* Bs, f4v (&acc)[8][4], const int kiters)
{
  const int tid  = threadIdx.x;
  const int lane = tid & 63, wv = tid >> 6;

  const int rh = tid >> 3;
  const int cs = (((tid & 7) ^ ((tid >> 3) & 7)) << 3);
  const h16* AgT = Abase + (long)rh * ASTRIDE + cs;
  const h16* BgT = Bbase + (long)rh * BSTRIDE + cs;
  h16* lA = As + tid * 8;
  h16* lB = Bs + tid * 8;

  auto stageA = [&](int kt, int half) {
    h16* d = lA + ((kt & 1) << 14) + (half << 13);
    const h16* g = AgT + (long)half * 128 * ASTRIDE + kt * 64;
    async16(g, d);
    async16(g + 64 * ASTRIDE, d + 4096);
  };
  auto stageB = [&](int kt, int half) {
    h16* d = lB + ((kt & 1) << 14) + (half << 13);
    const h16* g = BgT + (long)half * 128 * BSTRIDE + kt * 64;
    async16(g, d);
    async16(g + 64 * BSTRIDE, d + 4096);
  };

  const int wr = wv >> 2, wc = wv & 3;
  const int e0 = (((lane >> 4) ^ (lane & 7)) << 3);
  const int e1 = e0 ^ 32;
  const h16* pA0 = As + (wr * 128 + (lane & 15)) * 64 + e0;
  const h16* pA1 = pA0 + (e1 - e0);
  const h16* pB0 = Bs + (wc * 64 + (lane & 15)) * 64 + e0;
  const h16* pB1 = pB0 + (e1 - e0);

#pragma unroll
  for (int i = 0; i < 8; ++i)
#pragma unroll
    for (int j = 0; j < 4; ++j) { f4v z = {0.f, 0.f, 0.f, 0.f}; acc[i][j] = z; }

  // prologue: kt0 fully + A0(kt1); leave A0(kt1)'s 2 loads in flight.
  stageA(0, 0); stageA(0, 1); stageB(0, 0); stageB(0, 1); stageA(1, 0);
  asm volatile("s_waitcnt vmcnt(2)" ::: "memory");
  BARRIER();

#pragma unroll 1
  for (int kt = 0; kt < kiters; ++kt) {
    const int sb = (kt & 1) << 14;
    h8v ar[4][2], bL[2][2], bR[2][2];
    // ---- phase 1: TL -> acc[0-3][0-1] ----
#pragma unroll
    for (int i = 0; i < 4; ++i) {
      ar[i][0] = *(const h8v*)(pA0 + sb + i * 1024);
      ar[i][1] = *(const h8v*)(pA1 + sb + i * 1024);
    }
#pragma unroll
    for (int j = 0; j < 2; ++j) {
      bL[j][0] = *(const h8v*)(pB0 + sb + j * 1024);
      bL[j][1] = *(const h8v*)(pB1 + sb + j * 1024);
    }
    if (kt < kiters - 1) stageA(kt + 1, 1);
    BARRIER();
    __builtin_amdgcn_s_setprio(1);
#pragma unroll
    for (int i = 0; i < 4; ++i)
#pragma unroll
      for (int j = 0; j < 2; ++j) {
        acc[i][j] = MFMA16(ar[i][0], bL[j][0], acc[i][j], 0, 0, 0);
        acc[i][j] = MFMA16(ar[i][1], bL[j][1], acc[i][j], 0, 0, 0);
      }
    __builtin_amdgcn_s_setprio(0);
    BARRIER();
    // ---- phase 2: TR -> acc[0-3][2-3] ----
#pragma unroll
    for (int j = 0; j < 2; ++j) {
      bR[j][0] = *(const h8v*)(pB0 + sb + (j + 2) * 1024);
      bR[j][1] = *(const h8v*)(pB1 + sb + (j + 2) * 1024);
    }
    if (kt < kiters - 1) stageB(kt + 1, 0);
    BARRIER();
    __builtin_amdgcn_s_setprio(1);
#pragma unroll
    for (int i = 0; i < 4; ++i)
#pragma unroll
      for (int j = 0; j < 2; ++j) {
        acc[i][j + 2] = MFMA16(ar[i][0], bR[j][0], acc[i][j + 2], 0, 0, 0);
        acc[i][j + 2] = MFMA16(ar[i][1], bR[j][1], acc[i][j + 2], 0, 0, 0);
      }
    __builtin_amdgcn_s_setprio(0);
    BARRIER();
    // ---- phase 3: BR -> acc[4-7][2-3] (ar <- rows 64-127) ----
#pragma unroll
    for (int i = 0; i < 4; ++i) {
      ar[i][0] = *(const h8v*)(pA0 + sb + (i + 4) * 1024);
      ar[i][1] = *(const h8v*)(pA1 + sb + (i + 4) * 1024);
    }
    if (kt < kiters - 1) stageB(kt + 1, 1);
    BARRIER();
    __builtin_amdgcn_s_setprio(1);
#pragma unroll
    for (int i = 0; i < 4; ++i)
#pragma unroll
      for (int j = 0; j < 2; ++j) {
        acc[i + 4][j + 2] = MFMA16(ar[i][0], bR[j][0], acc[i + 4][j + 2], 0, 0, 0);
        acc[i + 4][j + 2] = MFMA16(ar[i][1], bR[j][1], acc[i + 4][j + 2], 0, 0, 0);
      }
    __builtin_amdgcn_s_setprio(0);
    BARRIER();
    // ---- phase 4: BL -> acc[4-7][0-1] (re-read bL) ----
#pragma unroll
    for (int j = 0; j < 2; ++j) {
      bL[j][0] = *(const h8v*)(pB0 + sb + j * 1024);
      bL[j][1] = *(const h8v*)(pB1 + sb + j * 1024);
    }
    if (kt < kiters - 2) {
      stageA(kt + 2, 0);
      asm volatile("s_waitcnt vmcnt(2)" ::: "memory");
    } else if (kt == kiters - 2) {
      asm volatile("s_waitcnt vmcnt(0)" ::: "memory");
    }
    BARRIER();
    __builtin_amdgcn_s_setprio(1);
#pragma unroll
    for (int i = 0; i < 4; ++i)
#pragma unroll
      for (int j = 0; j < 2; ++j) {
        acc[i + 4][j] = MFMA16(ar[i][0], bL[j][0], acc[i + 4][j], 0, 0, 0);
        acc[i + 4][j] = MFMA16(ar[i][1], bL[j][1], acc[i + 4][j], 0, 0, 0);
      }
    __builtin_amdgcn_s_setprio(0);
    BARRIER();
  }
}

// ---------------- merged prep kernel (src pad + conv-W transpose + lin-W cast) ----
#define NSRC_BLK 8252   // NBATCH*NPAD*DM/256
__global__ __launch_bounds__(256) void prep_all_kernel(
    const float* __restrict__ src,
    const float* __restrict__ Wq, const float* __restrict__ Wk, const float* __restrict__ Wv,
    const float* __restrict__ W1, const float* __restrict__ W2, const float* __restrict__ W3,
    h16* __restrict__ Xpad, h16* __restrict__ Wt, h16* __restrict__ Wl)
{
  __shared__ float plds[16][257];
  const int bi = blockIdx.x, tid = threadIdx.x;
  if (bi < NSRC_BLK) {
    int idx = bi * 256 + tid;
    int c = idx & 255;
    int row = idx >> 8;
    int b = row / NPAD;
    int n = row - b * NPAD;
    float v = 0.f;
    int ns = n - 7;
    if (ns >= 0 && ns < NNODE) v = src[((long)b * NNODE + ns) * DM + c];
    Xpad[idx] = (h16)v;
  } else if (bi < NSRC_BLK + 768) {
    // coalesced read of W[o][c][t], LDS transpose, coalesced write Wt[w][o][t][c]
    const int q = bi - NSRC_BLK;
    const int w = q >> 8, o = q & 255;
    const float* W = (w == 0) ? Wq : (w == 1) ? Wk : Wv;
    const float* base = W + (long)o * 4096;
    f4v r0 = *(const f4v*)(base + tid * 16);
    f4v r1 = *(const f4v*)(base + tid * 16 + 4);
    f4v r2 = *(const f4v*)(base + tid * 16 + 8);
    f4v r3 = *(const f4v*)(base + tid * 16 + 12);
#pragma unroll
    for (int k = 0; k < 4; ++k) {
      plds[k][tid] = r0[k]; plds[4 + k][tid] = r1[k];
      plds[8 + k][tid] = r2[k]; plds[12 + k][tid] = r3[k];
    }
    __syncthreads();
    const int t = tid >> 4, c0 = (tid & 15) * 16;
    h16* out = Wt + ((long)(w * 256 + o)) * 4096 + t * 256 + c0;
    h8v o0, o1;
#pragma unroll
    for (int k = 0; k < 8; ++k) { o0[k] = (h16)plds[t][c0 + k]; o1[k] = (h16)plds[t][c0 + 8 + k]; }
    *(h8v*)out = o0;
    *(h8v*)(out + 8) = o1;
  } else {
    int idx = (bi - NSRC_BLK - 768) * 256 + tid;   // over 3*65536
    int w = idx >> 16;
    int rem = idx & 65535;
    const float* W = (w == 0) ? W1 : (w == 1) ? W2 : W3;
    Wl[idx] = (h16)W[rem];
  }
}

// ---------------- conv GEMM: 256x256 tile, 8-phase pipeline, split-K x2 -----------
// Grid (32 Mtiles, 3 weights, 2 ksplits) = 192 blocks x 512 thr.
__global__ __launch_bounds__(512) void conv_gemm256_kernel(
    const h16* __restrict__ Xpad, const h16* __restrict__ Wt,
    h16* __restrict__ Qp, h16* __restrict__ Kp, h16* __restrict__ Vp)
{
  __shared__ __align__(16) h16 As[32768];   // [2 slots][256 rows][64 k]
  __shared__ __align__(16) h16 Bs[32768];
  const int lane = threadIdx.x & 63, wv = threadIdx.x >> 6;
  const int mt = blockIdx.x, w = blockIdx.y, ks = blockIdx.z;
  const int m0 = mt * 256;
  const int b  = m0 >> 11, n0 = m0 & 2047;

  const h16* Abase = Xpad + ((long)(b * NPAD + n0) << 8) + ((long)ks << 11);
  const h16* Bbase = Wt + ((long)w << 20) + ((long)ks << 11);

  f4v acc[8][4];
  gemm256_pipe<256, 4096>(Abase, Bbase, As, Bs, acc, 32);

  // epilogue: all outputs (incl. V) as [ks][m][c] f16 partials.
  h16* dst = ((w == 0) ? Qp : (w == 1) ? Kp : Vp) + (long)ks * QKELEM;
  const int wr = wv >> 2, wc = wv & 3;
  const int rb = (lane >> 4) * 4;
  const int cb = wc * 64 + (lane & 15);
  const int mrow0 = m0 + wr * 128;
#pragma unroll
  for (int i = 0; i < 8; ++i)
#pragma unroll
    for (int j = 0; j < 4; ++j) {
      const int gc = cb + j * 16;
#pragma unroll
      for (int e = 0; e < 4; ++e) {
        const int gr = mrow0 + i * 16 + rb + e;
        dst[(long)gr * 256 + gc] = (h16)acc[i][j][e];
      }
    }
}

// ---------------- conv reduce: sum 2 partials + bias -> Q,K [m][c]; V -> Vt[b][d][m]
__global__ __launch_bounds__(256) void conv_reduce_kernel(
    const h16* __restrict__ Qp, const h16* __restrict__ Kp, const h16* __restrict__ Vp,
    const float* __restrict__ bq, const float* __restrict__ bk, const float* __restrict__ bv,
    h16* __restrict__ Qb, h16* __restrict__ Kb, h16* __restrict__ Vt)
{
  __shared__ float T[64][65];
  const int bi = blockIdx.x, tid = threadIdx.x;
  if (bi < 2048) {
    const long gid = (long)bi * 256 + tid;
    const int which = gid >= (QKELEM / 8);
    const long e = (gid - (long)which * (QKELEM / 8)) * 8;
    const h16* P = which ? Kp : Qp;
    const float* bias = which ? bk : bq;
    h8v p0 = *(const h8v*)(P + e);
    h8v p1 = *(const h8v*)(P + QKELEM + e);
    const int c0 = (int)(e & 255);
    h8v o;
#pragma unroll
    for (int k = 0; k < 8; ++k) o[k] = (h16)((float)p0[k] + (float)p1[k] + bias[c0 + k]);
    *(h8v*)((which ? Kb : Qb) + e) = o;
  } else {
    const int q = bi - 2048;                 // 0..511: (8192/64) m-tiles x (256/64) c-tiles
    const int mt = q >> 2, ct = q & 3;
    const int m0 = mt * 64, c0 = ct * 64;
    const int b = m0 >> 11, n0 = m0 & 2047;
    const int rr = tid >> 3, cc = (tid & 7) * 8;
#pragma unroll
    for (int p = 0; p < 2; ++p) {
      const int r = p * 32 + rr;
      const long so = (long)(m0 + r) * 256 + c0 + cc;
      h8v p0 = *(const h8v*)(Vp + so);
      h8v p1 = *(const h8v*)(Vp + QKELEM + so);
#pragma unroll
      for (int e = 0; e < 8; ++e) T[r][cc + e] = (float)p0[e] + (float)p1[e];
    }
    __syncthreads();
#pragma unroll
    for (int p = 0; p < 2; ++p) {
      const int d = p * 32 + rr;
      const float bias_v = bv[c0 + d];
      h8v o;
#pragma unroll
      for (int e = 0; e < 8; ++e) o[e] = (h16)(T[cc + e][d] + bias_v);
      *(h8v*)(Vt + ((long)(b * 256 + c0 + d)) * 2048 + n0 + cc) = o;
    }
  }
}

// ---------------- scores GEMM (128^2, proven core) + FUSED mask/dis ---------------
// Sh[b][n][m] = adj>0 ? (Q.K^T * scale - dis) : -30000  (f16)
// Masked = -30000: exp(-30000 - m) underflows to exactly 0; an all-masked row
// degenerates to uniform 1/2048, matching softmax over all -1e9. The 128 MB of
// dis/adj reads live in the epilogue, hidden by co-resident blocks' MFMA phases
// (~3 blocks/CU at 16 KB LDS).
__global__ __launch_bounds__(256) void scores_gemm_kernel(
    const h16* __restrict__ Q, const h16* __restrict__ Km,
    const float* __restrict__ dis, const int* __restrict__ adj,
    h16* __restrict__ Sh)
{
  __shared__ __align__(16) h16 As[4096];
  __shared__ __align__(16) h16 Bs[4096];
  const int nt = blockIdx.x, mt = blockIdx.y, b = blockIdx.z;
  const h16* Abase = Q + ((long)b * NNODE + nt * 128) * 256;
  const h16* Bbase = Km + ((long)b * NNODE + mt * 128) * 256;
  f4v acc[4][4];
  zero_acc(acc);
  gemm_tile(Abase, 256, Bbase, 256, As, Bs, acc, 8);

  const int lane = threadIdx.x & 63, wv = threadIdx.x >> 6;
  const int rbase = (wv & 1) * 64 + (lane >> 4) * 4;
  const int cbase = (wv >> 1) * 64 + (lane & 15);
  const long base = (long)b * NNODE * NNODE;
#pragma unroll
  for (int i = 0; i < 4; ++i) {
#pragma unroll
    for (int e = 0; e < 4; ++e) {
      const long row = nt * 128 + rbase + i * 16 + e;
      const long ro = base + row * 2048 + mt * 128;
#pragma unroll
      for (int j = 0; j < 4; ++j) {
        const int col = cbase + j * 16;
        const int a = adj[ro + col];
        const float dd = dis[ro + col];
        const float sv = acc[i][j][e] * 0.0625f - dd;
        Sh[ro + col] = (a > 0) ? (h16)sv : (h16)(-30000.0f);
      }
    }
  }
}

// ---------------- fused softmax + x_lst_new + attn (mask pre-applied) -------------
// R4 proven structure (block per row, dense f4v mapping, s[8], no spill), minus the
// dis/adj streams (now folded into scores). 192 MB total traffic.
__global__ __launch_bounds__(256) void softmax_kernel(
    h16* __restrict__ Sh, const float* __restrict__ x_lst, float* __restrict__ out_x)
{
  const int r = blockIdx.x;                 // 0..8191 (b*2048+n)
  const long ro = (long)r * 2048;
  const int tid = threadIdx.x, lane = tid & 63, wv = tid >> 6;
  const int j0 = tid * 4;
  __shared__ float wmax[4], wsum[4];

  h4v sv0 = *(const h4v*)(Sh + ro + j0);
  h4v sv1 = *(const h4v*)(Sh + ro + 1024 + j0);

  float s[8];
#pragma unroll
  for (int k = 0; k < 4; ++k) { s[k] = (float)sv0[k]; s[k + 4] = (float)sv1[k]; }

  float m = s[0];
#pragma unroll
  for (int k = 1; k < 8; ++k) m = fmaxf(m, s[k]);
#pragma unroll
  for (int off = 32; off > 0; off >>= 1) m = fmaxf(m, __shfl_xor(m, off, 64));
  if (lane == 0) wmax[wv] = m;
  __syncthreads();
  m = fmaxf(fmaxf(wmax[0], wmax[1]), fmaxf(wmax[2], wmax[3]));

  float p[8], ls = 0.f;
#pragma unroll
  for (int k = 0; k < 8; ++k) { p[k] = __expf(s[k] - m); ls += p[k]; }
#pragma unroll
  for (int off = 32; off > 0; off >>= 1) ls += __shfl_xor(ls, off, 64);
  if (lane == 0) wsum[wv] = ls;
  __syncthreads();
  const float inv = 1.0f / (wsum[0] + wsum[1] + wsum[2] + wsum[3]);

  f4v x0 = *(const f4v*)(x_lst + ro + j0);
  f4v x1 = *(const f4v*)(x_lst + ro + 1024 + j0);
  f4v o0, o1;
  h4v pv0, pv1;
#pragma unroll
  for (int k = 0; k < 4; ++k) {
    const float a = p[k] * inv, bq = p[k + 4] * inv;
    o0[k] = x0[k] + a; o1[k] = x1[k] + bq;
    pv0[k] = (h16)a; pv1[k] = (h16)bq;
  }
  *(f4v*)(out_x + ro + j0) = o0;
  *(f4v*)(out_x + ro + 1024 + j0) = o1;
  *(h4v*)(Sh + ro + j0) = pv0;
  *(h4v*)(Sh + ro + 1024 + j0) = pv1;
}

// ---------------- AV GEMM (split-K x2): X1p[ks][m][d] f16 partials ----------------
__global__ __launch_bounds__(256) void av_gemm_kernel(
    const h16* __restrict__ Attn, const h16* __restrict__ Vt, h16* __restrict__ X1p)
{
  __shared__ __align__(16) h16 As[4096];
  __shared__ __align__(16) h16 Bs[4096];
  const int nt = blockIdx.x, b = blockIdx.z;
  const int ct = blockIdx.y & 1, ks = blockIdx.y >> 1;
  const h16* Abase = Attn + ((long)b * NNODE + nt * 128) * 2048 + ks * 1024;
  const h16* Bbase = Vt + ((long)b * 256 + ct * 128) * 2048 + ks * 1024;
  f4v acc[4][4];
  zero_acc(acc);
  gemm_tile(Abase, 2048, Bbase, 2048, As, Bs, acc, 32);

  const int lane = threadIdx.x & 63, wv = threadIdx.x >> 6;
  const int rbase = (wv & 1) * 64 + (lane >> 4) * 4;
  const int cbase = (wv >> 1) * 64 + (lane & 15);
  h16* dst = X1p + (long)ks * PARTN;
#pragma unroll
  for (int i = 0; i < 4; ++i) {
#pragma unroll
    for (int e = 0; e < 4; ++e) {
      const long row = (long)b * NNODE + nt * 128 + rbase + i * 16 + e;
#pragma unroll
      for (int j = 0; j < 4; ++j) {
        const int col = ct * 128 + cbase + j * 16;
        dst[row * 256 + col] = (h16)acc[i][j][e];
      }
    }
  }
}

// ---------------- fused residual + partial-sum + LayerNorm1 -----------------------
__device__ __forceinline__ float wred_sum(float v) {
#pragma unroll
  for (int off = 32; off > 0; off >>= 1) v += __shfl_xor(v, off, 64);
  return v;
}

__global__ __launch_bounds__(256) void ln1_kernel(
    const float* __restrict__ X, const h16* __restrict__ Y, const h16* __restrict__ Y2,
    const float* __restrict__ g, const float* __restrict__ bb,
    float* __restrict__ outF, h16* __restrict__ outH)
{
  const int wv = threadIdx.x >> 6, lane = threadIdx.x & 63;
  const long r = (long)blockIdx.x * 4 + wv;
  const long off = r * 256 + lane * 4;
  f4v x = *(const f4v*)(X + off);
  h4v y = *(const h4v*)(Y + off);
  h4v y2 = *(const h4v*)(Y2 + off);
  float v[4];
  float sum = 0.f, sq = 0.f;
#pragma unroll
  for (int k = 0; k < 4; ++k) {
    v[k] = x[k] + (float)y[k] + (float)y2[k];
    sum += v[k]; sq += v[k] * v[k];
  }
  sum = wred_sum(sum);
  sq  = wred_sum(sq);
  const float mu = sum * (1.0f / 256.0f);
  const float var = sq * (1.0f / 256.0f) - mu * mu;
  const float rs = rsqrtf(var + 1e-5f);
  f4v gg = *(const f4v*)(g + lane * 4);
  f4v be = *(const f4v*)(bb + lane * 4);
  f4v o;
#pragma unroll
  for (int k = 0; k < 4; ++k) o[k] = (v[k] - mu) * rs * gg[k] + be[k];
  *(f4v*)(outF + off) = o;
  h4v hv;
#pragma unroll
  for (int k = 0; k < 4; ++k) hv[k] = (h16)o[k];
  *(h4v*)(outH + off) = hv;
}

// ---------------- fused 3-layer MLP + residual + LayerNorm2 -----------------------
__global__ __launch_bounds__(256) void mlp_fused_kernel(
    const h16* __restrict__ H16, const float* __restrict__ Hf,
    const h16* __restrict__ Wl,
    const float* __restrict__ b1, const float* __restrict__ b2, const float* __restrict__ b3,
    const float* __restrict__ g2, const float* __restrict__ be2,
    float* __restrict__ out_h)
{
  __shared__ h16 Xa[32][264];
  __shared__ h16 Xb[32][264];
  __shared__ __align__(16) h16 Bs[8192];      // 256 out-cols x 32 k
  const int tid = threadIdx.x, lane = tid & 63, wv = tid >> 6;
  const int m0 = blockIdx.x * 32;

  { // load LN1 output rows into Xa (coalesced global, padded LDS writes)
    const int r = tid >> 3, cq = (tid & 7) * 32;
    const h16* s = H16 + (long)(m0 + r) * 256 + cq;
#pragma unroll
    for (int k = 0; k < 4; ++k)
      *(h8v*)&Xa[r][cq + k * 8] = *(const h8v*)(s + k * 8);
  }

  const int srow = tid >> 2;
  const int sch  = ((tid & 3) ^ ((tid >> 3) & 3)) * 8;
  h16* lB = Bs + tid * 8;
  const int quad = lane >> 4;
  const float* biases[3] = {b1, b2, b3};

  for (int layer = 0; layer < 3; ++layer) {
    const h16* W = Wl + layer * 65536;
    const h16 (*Xi)[264] = (layer == 1) ? (const h16(*)[264])Xb : (const h16(*)[264])Xa;
    h16 (*Xo)[264] = (layer == 1) ? Xa : Xb;
    f4v acc[2][4];
#pragma unroll
    for (int i = 0; i < 2; ++i)
#pragma unroll
      for (int j = 0; j < 4; ++j) { f4v z = {0.f,0.f,0.f,0.f}; acc[i][j] = z; }

    for (int kt = 0; kt < 8; ++kt) {
      __syncthreads();
      const h16* gB = W + (long)srow * 256 + kt * 32 + sch;
      async16(gB, lB);
      async16(gB + 64 * 256, lB + 64 * 32);
      async16(gB + 128 * 256, lB + 128 * 32);
      async16(gB + 192 * 256, lB + 192 * 32);
      asm volatile("s_waitcnt vmcnt(0)" ::: "memory");
      __syncthreads();
      h8v af[2], bf[4];
#pragma unroll
      for (int i = 0; i < 2; ++i)
        af[i] = *(const h8v*)&Xi[i * 16 + (lane & 15)][kt * 32 + quad * 8];
#pragma unroll
      for (int j = 0; j < 4; ++j) {
        const int n = wv * 64 + j * 16 + (lane & 15);
        const int q = (quad ^ ((n >> 1) & 3)) * 8;
        bf[j] = *(const h8v*)(Bs + n * 32 + q);
      }
#pragma unroll
      for (int i = 0; i < 2; ++i)
#pragma unroll
        for (int j = 0; j < 4; ++j)
          acc[i][j] = MFMA16(af[i], bf[j], acc[i][j], 0, 0, 0);
    }
    // epilogue: bias (+leaky for layers 0/1), write to Xo (other buffer -> no race)
    const int rb = quad * 4;
    const int cb = wv * 64 + (lane & 15);
    const float* bias = biases[layer];
    const bool leaky = (layer < 2);
#pragma unroll
    for (int j = 0; j < 4; ++j) {
      const int col = cb + j * 16;
      const float bv = bias[col];
#pragma unroll
      for (int i = 0; i < 2; ++i)
#pragma unroll
        for (int e = 0; e < 4; ++e) {
          float v = acc[i][j][e] + bv;
          if (leaky) v = (v >= 0.f) ? v : 0.01f * v;
          Xo[i * 16 + rb + e][col] = (h16)v;
        }
    }
  }
  __syncthreads();

  // LN2: rows in Xb (layer-3 out), residual Hf, write out_h. 8 threads/row.
  const int r = tid >> 3, c0 = (tid & 7) * 32;
  const float* hrow = Hf + (long)(m0 + r) * 256 + c0;
  float v[32];
  float s = 0.f, sq = 0.f;
#pragma unroll
  for (int k8 = 0; k8 < 8; ++k8) {
    f4v h4 = *(const f4v*)(hrow + k8 * 4);
#pragma unroll
    for (int e = 0; e < 4; ++e) {
      float t = (float)Xb[r][c0 + k8 * 4 + e] + h4[e];
      v[k8 * 4 + e] = t; s += t; sq += t * t;
    }
  }
#pragma unroll
  for (int off = 1; off < 8; off <<= 1) { s += __shfl_xor(s, off, 64); sq += __shfl_xor(sq, off, 64); }
  const float mu = s * (1.0f / 256.0f);
  const float var = sq * (1.0f / 256.0f) - mu * mu;
  const float rs = rsqrtf(var + 1e-5f);
  float* orow = out_h + (long)(m0 + r) * 256 + c0;
#pragma unroll
  for (int k8 = 0; k8 < 8; ++k8) {
    f4v gg = *(const f4v*)(g2 + c0 + k8 * 4);
    f4v be = *(const f4v*)(be2 + c0 + k8 * 4);
    f4v o;
#pragma unroll
    for (int e = 0; e < 4; ++e) o[e] = (v[k8 * 4 + e] - mu) * rs * gg[e] + be[e];
    *(f4v*)(orow + k8 * 4) = o;
  }
}

// ---------------- launch ----------------------------------------------------------
extern "C" void kernel_launch(void* const* d_in, const int* in_sizes, int n_in,
                              void* d_out, int out_size, void* d_ws, size_t ws_size,
                              hipStream_t stream)
{
  const float* src  = (const float*)d_in[0];
  const float* xlst = (const float*)d_in[1];
  const int*   adj  = (const int*)d_in[2];
  const float* dis  = (const float*)d_in[3];
  const float* Wq   = (const float*)d_in[4];
  const float* bq   = (const float*)d_in[5];
  const float* Wk   = (const float*)d_in[6];
  const float* bk   = (const float*)d_in[7];
  const float* Wv   = (const float*)d_in[8];
  const float* bvp  = (const float*)d_in[9];
  const float* W1   = (const float*)d_in[10];
  const float* b1   = (const float*)d_in[11];
  const float* W2   = (const float*)d_in[12];
  const float* b2   = (const float*)d_in[13];
  const float* W3   = (const float*)d_in[14];
  const float* b3   = (const float*)d_in[15];
  const float* g1   = (const float*)d_in[16];
  const float* be1  = (const float*)d_in[17];
  const float* g2   = (const float*)d_in[18];
  const float* be2  = (const float*)d_in[19];
  (void)in_sizes; (void)n_in; (void)out_size; (void)ws_size;

  char* ws = (char*)d_ws;
  size_t off = 0;
  auto alloc = [&](size_t bytes) -> void* {
    void* p = ws + off;
    off += (bytes + 1023) & ~(size_t)1023;
    return p;
  };
  h16*   Xpad = (h16*)  alloc((size_t)NBATCH * NPAD * DM * 2);       // 4.2 MB
  h16*   Wt   = (h16*)  alloc((size_t)3 * 256 * 4096 * 2);           // 6.3 MB
  h16*   Wl   = (h16*)  alloc((size_t)3 * 256 * 256 * 2);            // 0.4 MB
  h16*   Qb   = (h16*)  alloc((size_t)QKELEM * 2);                   // 4 MB
  h16*   Kb   = (h16*)  alloc((size_t)QKELEM * 2);                   // 4 MB
  h16*   Vt   = (h16*)  alloc((size_t)QKELEM * 2);                   // 4 MB
  // union region R: conv partials (25 MB, dead after reduce) overlap Sh/X1p.
  char*  R    = (char*) alloc((size_t)66000 * 1024);                 // ~64.5 MB
  h16*   Qp   = (h16*)R;                                   // [2][m][c]  8.4 MB
  h16*   Kp   = (h16*)(R + (size_t)2 * QKELEM * 2);        // [2][m][c]  8.4 MB
  h16*   Vp   = (h16*)(R + (size_t)4 * QKELEM * 2);        // [2][m][c]  8.4 MB
  h16*   Sh   = (h16*)R;                                   // 32 MB (over dead Qp/Kp/Vp)
  h16*   X1p  = (h16*)(R + (size_t)8 * QKELEM * 2);        // 8.4 MB (just past Sh)
  float* H    = (float*)(R + (size_t)12 * QKELEM * 2);     // 8 MB
  h16*   H16  = (h16*)((char*)H + (size_t)PARTN * 4);      // 4 MB

  float* out_h = (float*)d_out;                        // [B,N,d]
  float* out_x = out_h + (size_t)NBATCH * NNODE * DM;  // [B,N,N]

  prep_all_kernel<<<NSRC_BLK + 768 + 768, 256, 0, stream>>>(
      src, Wq, Wk, Wv, W1, W2, W3, Xpad, Wt, Wl);
  conv_gemm256_kernel<<<dim3(32, 3, 2), 512, 0, stream>>>(Xpad, Wt, Qp, Kp, Vp);
  conv_reduce_kernel<<<2048 + 512, 256, 0, stream>>>(
      Qp, Kp, Vp, bq, bk, bvp, Qb, Kb, Vt);
  scores_gemm_kernel<<<dim3(16, 16, 4), 256, 0, stream>>>(Qb, Kb, dis, adj, Sh);
  softmax_kernel<<<NBATCH * NNODE, 256, 0, stream>>>(Sh, xlst, out_x);
  av_gemm_kernel<<<dim3(16, 4, 4), 256, 0, stream>>>(Sh, Vt, X1p);
  ln1_kernel<<<(NBATCH * NNODE) / 4, 256, 0, stream>>>(src, X1p, X1p + PARTN, g1, be1, H, H16);
  mlp_fused_kernel<<<NBATCH * NNODE / 32, 256, 0, stream>>>(
      H16, H, Wl, b1, b2, b3, g2, be2, out_h);
}

// Round 7
// 413.050 us; speedup vs baseline: 1.0315x; 1.0202x over previous
//
#include <hip/hip_runtime.h>
#include <stdint.h>

typedef _Float16 h16;
typedef _Float16 h4v __attribute__((ext_vector_type(4)));
typedef _Float16 h8v __attribute__((ext_vector_type(8)));
typedef float    f4v __attribute__((ext_vector_type(4)));
typedef int      i4v __attribute__((ext_vector_type(4)));

#define NBATCH 4
#define NNODE  2048
#define DM     256
#define NPAD   2063       // NNODE + 15 (SAME pad: 7 low, 8 high)
#define QKELEM 2097152    // 8192*256 elements
#define PARTN  (8192 * 256)

// ---------------- async global->LDS (16B per lane, wave-uniform base + lane*16) ----
__device__ __forceinline__ void async16(const void* g, void* l) {
#if __has_builtin(__builtin_amdgcn_global_load_lds)
  __builtin_amdgcn_global_load_lds((__attribute__((address_space(1))) void*)g,
                                   (__attribute__((address_space(3))) void*)l, 16, 0, 0);
#else
  *(f4v*)l = *(const f4v*)g;
#endif
}

#define BARRIER() do { asm volatile("" ::: "memory"); __builtin_amdgcn_s_barrier(); asm volatile("" ::: "memory"); } while (0)
#define MFMA16 __builtin_amdgcn_mfma_f32_16x16x32_f16

// ---------------- shared 128x128xBK32 MFMA GEMM core (round-2 proven version) -----
// Used by the AV GEMM. ~3 blocks/CU co-residency hides epilogue memory tails.
__device__ __forceinline__ void gemm_tile(
    const h16* Abase, int astride,
    const h16* Bbase, int bstride,
    h16* As, h16* Bs, f4v acc[4][4], int kiters)
{
  const int tid  = threadIdx.x;
  const int lane = tid & 63;
  const int wv   = tid >> 6;
  const int srow = tid >> 2;
  const int sch  = ((tid & 3) ^ ((tid >> 3) & 3)) * 8;   // swizzled source chunk
  const h16* gA0 = Abase + (long)srow * astride + sch;
  const h16* gA1 = Abase + (long)(srow + 64) * astride + sch;
  const h16* gB0 = Bbase + (long)srow * bstride + sch;
  const h16* gB1 = Bbase + (long)(srow + 64) * bstride + sch;
  h16* lA0 = As + tid * 8;
  h16* lA1 = As + 2048 + tid * 8;
  h16* lB0 = Bs + tid * 8;
  h16* lB1 = Bs + 2048 + tid * 8;
  const int swz = ((lane & 15) >> 1) & 3;
  const int qq  = ((lane >> 4) ^ swz) * 8;
  const int amr = ((wv & 1) * 64 + (lane & 15)) * 32 + qq;
  const int bnr = ((wv >> 1) * 64 + (lane & 15)) * 32 + qq;

  for (int kt = 0; kt < kiters; ++kt) {
    const int k0 = kt * 32;
    __syncthreads();
    async16(gA0 + k0, lA0);
    async16(gA1 + k0, lA1);
    async16(gB0 + k0, lB0);
    async16(gB1 + k0, lB1);
    asm volatile("s_waitcnt vmcnt(0)" ::: "memory");
    __syncthreads();
    h8v af[4], bf[4];
#pragma unroll
    for (int i = 0; i < 4; ++i) af[i] = *(const h8v*)(As + amr + i * 512);
#pragma unroll
    for (int j = 0; j < 4; ++j) bf[j] = *(const h8v*)(Bs + bnr + j * 512);
#pragma unroll
    for (int i = 0; i < 4; ++i)
#pragma unroll
      for (int j = 0; j < 4; ++j)
        acc[i][j] = MFMA16(af[i], bf[j], acc[i][j], 0, 0, 0);
  }
}

__device__ __forceinline__ void zero_acc(f4v acc[4][4]) {
#pragma unroll
  for (int i = 0; i < 4; ++i)
#pragma unroll
    for (int j = 0; j < 4; ++j) {
      f4v z = {0.f, 0.f, 0.f, 0.f};
      acc[i][j] = z;
    }
}

// ---------------- 256x256-tile 8-phase counted-vmcnt GEMM pipeline (conv only) -----
template<int ASTRIDE, int BSTRIDE>
__device__ __forceinline__ void gemm256_pipe(
    const h16* __restrict__ Abase, const h16* __restrict__ Bbase,
    h16* As, h16* Bs, f4v (&acc)[8][4], const int kiters)
{
  const int tid  = threadIdx.x;
  const int lane = tid & 63, wv = tid >> 6;

  const int rh = tid >> 3;
  const int cs = (((tid & 7) ^ ((tid >> 3) & 7)) << 3);
  const h16* AgT = Abase + (long)rh * ASTRIDE + cs;
  const h16* BgT = Bbase + (long)rh * BSTRIDE + cs;
  h16* lA = As + tid * 8;
  h16* lB = Bs + tid * 8;

  auto stageA = [&](int kt, int half) {
    h16* d = lA + ((kt & 1) << 14) + (half << 13);
    const h16* g = AgT + (long)half * 128 * ASTRIDE + kt * 64;
    async16(g, d);
    async16(g + 64 * ASTRIDE, d + 4096);
  };
  auto stageB = [&](int kt, int half) {
    h16* d = lB + ((kt & 1) << 14) + (half << 13);
    const h16* g = BgT + (long)half * 128 * BSTRIDE + kt * 64;
    async16(g, d);
    async16(g + 64 * BSTRIDE, d + 4096);
  };

  const int wr = wv >> 2, wc = wv & 3;
  const int e0 = (((lane >> 4) ^ (lane & 7)) << 3);
  const int e1 = e0 ^ 32;
  const h16* pA0 = As + (wr * 128 + (lane & 15)) * 64 + e0;
  const h16* pA1 = pA0 + (e1 - e0);
  const h16* pB0 = Bs + (wc * 64 + (lane & 15)) * 64 + e0;
  const h16* pB1 = pB0 + (e1 - e0);

#pragma unroll
  for (int i = 0; i < 8; ++i)
#pragma unroll
    for (int j = 0; j < 4; ++j) { f4v z = {0.f, 0.f, 0.f, 0.f}; acc[i][j] = z; }

  // prologue: kt0 fully + A0(kt1); leave A0(kt1)'s 2 loads in flight.
  stageA(0, 0); stageA(0, 1); stageB(0, 0); stageB(0, 1); stageA(1, 0);
  asm volatile("s_waitcnt vmcnt(2)" ::: "memory");
  BARRIER();

#pragma unroll 1
  for (int kt = 0; kt < kiters; ++kt) {
    const int sb = (kt & 1) << 14;
    h8v ar[4][2], bL[2][2], bR[2][2];
    // ---- phase 1: TL -> acc[0-3][0-1] ----
#pragma unroll
    for (int i = 0; i < 4; ++i) {
      ar[i][0] = *(const h8v*)(pA0 + sb + i * 1024);
      ar[i][1] = *(const h8v*)(pA1 + sb + i * 1024);
    }
#pragma unroll
    for (int j = 0; j < 2; ++j) {
      bL[j][0] = *(const h8v*)(pB0 + sb + j * 1024);
      bL[j][1] = *(const h8v*)(pB1 + sb + j * 1024);
    }
    if (kt < kiters - 1) stageA(kt + 1, 1);
    BARRIER();
    __builtin_amdgcn_s_setprio(1);
#pragma unroll
    for (int i = 0; i < 4; ++i)
#pragma unroll
      for (int j = 0; j < 2; ++j) {
        acc[i][j] = MFMA16(ar[i][0], bL[j][0], acc[i][j], 0, 0, 0);
        acc[i][j] = MFMA16(ar[i][1], bL[j][1], acc[i][j], 0, 0, 0);
      }
    __builtin_amdgcn_s_setprio(0);
    BARRIER();
    // ---- phase 2: TR -> acc[0-3][2-3] ----
#pragma unroll
    for (int j = 0; j < 2; ++j) {
      bR[j][0] = *(const h8v*)(pB0 + sb + (j + 2) * 1024);
      bR[j][1] = *(const h8v*)(pB1 + sb + (j + 2) * 1024);
    }
    if (kt < kiters - 1) stageB(kt + 1, 0);
    BARRIER();
    __builtin_amdgcn_s_setprio(1);
#pragma unroll
    for (int i = 0; i < 4; ++i)
#pragma unroll
      for (int j = 0; j < 2; ++j) {
        acc[i][j + 2] = MFMA16(ar[i][0], bR[j][0], acc[i][j + 2], 0, 0, 0);
        acc[i][j + 2] = MFMA16(ar[i][1], bR[j][1], acc[i][j + 2], 0, 0, 0);
      }
    __builtin_amdgcn_s_setprio(0);
    BARRIER();
    // ---- phase 3: BR -> acc[4-7][2-3] (ar <- rows 64-127) ----
#pragma unroll
    for (int i = 0; i < 4; ++i) {
      ar[i][0] = *(const h8v*)(pA0 + sb + (i + 4) * 1024);
      ar[i][1] = *(const h8v*)(pA1 + sb + (i + 4) * 1024);
    }
    if (kt < kiters - 1) stageB(kt + 1, 1);
    BARRIER();
    __builtin_amdgcn_s_setprio(1);
#pragma unroll
    for (int i = 0; i < 4; ++i)
#pragma unroll
      for (int j = 0; j < 2; ++j) {
        acc[i + 4][j + 2] = MFMA16(ar[i][0], bR[j][0], acc[i + 4][j + 2], 0, 0, 0);
        acc[i + 4][j + 2] = MFMA16(ar[i][1], bR[j][1], acc[i + 4][j + 2], 0, 0, 0);
      }
    __builtin_amdgcn_s_setprio(0);
    BARRIER();
    // ---- phase 4: BL -> acc[4-7][0-1] (re-read bL) ----
#pragma unroll
    for (int j = 0; j < 2; ++j) {
      bL[j][0] = *(const h8v*)(pB0 + sb + j * 1024);
      bL[j][1] = *(const h8v*)(pB1 + sb + j * 1024);
    }
    if (kt < kiters - 2) {
      stageA(kt + 2, 0);
      asm volatile("s_waitcnt vmcnt(2)" ::: "memory");
    } else if (kt == kiters - 2) {
      asm volatile("s_waitcnt vmcnt(0)" ::: "memory");
    }
    BARRIER();
    __builtin_amdgcn_s_setprio(1);
#pragma unroll
    for (int i = 0; i < 4; ++i)
#pragma unroll
      for (int j = 0; j < 2; ++j) {
        acc[i + 4][j] = MFMA16(ar[i][0], bL[j][0], acc[i + 4][j], 0, 0, 0);
        acc[i + 4][j] = MFMA16(ar[i][1], bL[j][1], acc[i + 4][j], 0, 0, 0);
      }
    __builtin_amdgcn_s_setprio(0);
    BARRIER();
  }
}

// ---------------- merged prep kernel (src pad + conv-W transpose + lin-W cast) ----
#define NSRC_BLK 8252   // NBATCH*NPAD*DM/256
__global__ __launch_bounds__(256) void prep_all_kernel(
    const float* __restrict__ src,
    const float* __restrict__ Wq, const float* __restrict__ Wk, const float* __restrict__ Wv,
    const float* __restrict__ W1, const float* __restrict__ W2, const float* __restrict__ W3,
    h16* __restrict__ Xpad, h16* __restrict__ Wt, h16* __restrict__ Wl)
{
  __shared__ float plds[16][257];
  const int bi = blockIdx.x, tid = threadIdx.x;
  if (bi < NSRC_BLK) {
    int idx = bi * 256 + tid;
    int c = idx & 255;
    int row = idx >> 8;
    int b = row / NPAD;
    int n = row - b * NPAD;
    float v = 0.f;
    int ns = n - 7;
    if (ns >= 0 && ns < NNODE) v = src[((long)b * NNODE + ns) * DM + c];
    Xpad[idx] = (h16)v;
  } else if (bi < NSRC_BLK + 768) {
    // coalesced read of W[o][c][t], LDS transpose, coalesced write Wt[w][o][t][c]
    const int q = bi - NSRC_BLK;
    const int w = q >> 8, o = q & 255;
    const float* W = (w == 0) ? Wq : (w == 1) ? Wk : Wv;
    const float* base = W + (long)o * 4096;
    f4v r0 = *(const f4v*)(base + tid * 16);
    f4v r1 = *(const f4v*)(base + tid * 16 + 4);
    f4v r2 = *(const f4v*)(base + tid * 16 + 8);
    f4v r3 = *(const f4v*)(base + tid * 16 + 12);
#pragma unroll
    for (int k = 0; k < 4; ++k) {
      plds[k][tid] = r0[k]; plds[4 + k][tid] = r1[k];
      plds[8 + k][tid] = r2[k]; plds[12 + k][tid] = r3[k];
    }
    __syncthreads();
    const int t = tid >> 4, c0 = (tid & 15) * 16;
    h16* out = Wt + ((long)(w * 256 + o)) * 4096 + t * 256 + c0;
    h8v o0, o1;
#pragma unroll
    for (int k = 0; k < 8; ++k) { o0[k] = (h16)plds[t][c0 + k]; o1[k] = (h16)plds[t][c0 + 8 + k]; }
    *(h8v*)out = o0;
    *(h8v*)(out + 8) = o1;
  } else {
    int idx = (bi - NSRC_BLK - 768) * 256 + tid;   // over 3*65536
    int w = idx >> 16;
    int rem = idx & 65535;
    const float* W = (w == 0) ? W1 : (w == 1) ? W2 : W3;
    Wl[idx] = (h16)W[rem];
  }
}

// ---------------- conv GEMM: 256x256 tile, 8-phase pipeline, split-K x2 -----------
// Grid (32 Mtiles, 3 weights, 2 ksplits) = 192 blocks x 512 thr.
__global__ __launch_bounds__(512) void conv_gemm256_kernel(
    const h16* __restrict__ Xpad, const h16* __restrict__ Wt,
    h16* __restrict__ Qp, h16* __restrict__ Kp, h16* __restrict__ Vp)
{
  __shared__ __align__(16) h16 As[32768];   // [2 slots][256 rows][64 k]
  __shared__ __align__(16) h16 Bs[32768];
  const int lane = threadIdx.x & 63, wv = threadIdx.x >> 6;
  const int mt = blockIdx.x, w = blockIdx.y, ks = blockIdx.z;
  const int m0 = mt * 256;
  const int b  = m0 >> 11, n0 = m0 & 2047;

  const h16* Abase = Xpad + ((long)(b * NPAD + n0) << 8) + ((long)ks << 11);
  const h16* Bbase = Wt + ((long)w << 20) + ((long)ks << 11);

  f4v acc[8][4];
  gemm256_pipe<256, 4096>(Abase, Bbase, As, Bs, acc, 32);

  // epilogue: all outputs (incl. V) as [ks][m][c] f16 partials.
  h16* dst = ((w == 0) ? Qp : (w == 1) ? Kp : Vp) + (long)ks * QKELEM;
  const int wr = wv >> 2, wc = wv & 3;
  const int rb = (lane >> 4) * 4;
  const int cb = wc * 64 + (lane & 15);
  const int mrow0 = m0 + wr * 128;
#pragma unroll
  for (int i = 0; i < 8; ++i)
#pragma unroll
    for (int j = 0; j < 4; ++j) {
      const int gc = cb + j * 16;
#pragma unroll
      for (int e = 0; e < 4; ++e) {
        const int gr = mrow0 + i * 16 + rb + e;
        dst[(long)gr * 256 + gc] = (h16)acc[i][j][e];
      }
    }
}

// ---------------- conv reduce: sum 2 partials + bias -> Q,K [m][c]; V -> Vt[b][d][m]
__global__ __launch_bounds__(256) void conv_reduce_kernel(
    const h16* __restrict__ Qp, const h16* __restrict__ Kp, const h16* __restrict__ Vp,
    const float* __restrict__ bq, const float* __restrict__ bk, const float* __restrict__ bv,
    h16* __restrict__ Qb, h16* __restrict__ Kb, h16* __restrict__ Vt)
{
  __shared__ float T[64][65];
  const int bi = blockIdx.x, tid = threadIdx.x;
  if (bi < 2048) {
    const long gid = (long)bi * 256 + tid;
    const int which = gid >= (QKELEM / 8);
    const long e = (gid - (long)which * (QKELEM / 8)) * 8;
    const h16* P = which ? Kp : Qp;
    const float* bias = which ? bk : bq;
    h8v p0 = *(const h8v*)(P + e);
    h8v p1 = *(const h8v*)(P + QKELEM + e);
    const int c0 = (int)(e & 255);
    h8v o;
#pragma unroll
    for (int k = 0; k < 8; ++k) o[k] = (h16)((float)p0[k] + (float)p1[k] + bias[c0 + k]);
    *(h8v*)((which ? Kb : Qb) + e) = o;
  } else {
    const int q = bi - 2048;                 // 0..511: (8192/64) m-tiles x (256/64) c-tiles
    const int mt = q >> 2, ct = q & 3;
    const int m0 = mt * 64, c0 = ct * 64;
    const int b = m0 >> 11, n0 = m0 & 2047;
    const int rr = tid >> 3, cc = (tid & 7) * 8;
#pragma unroll
    for (int p = 0; p < 2; ++p) {
      const int r = p * 32 + rr;
      const long so = (long)(m0 + r) * 256 + c0 + cc;
      h8v p0 = *(const h8v*)(Vp + so);
      h8v p1 = *(const h8v*)(Vp + QKELEM + so);
#pragma unroll
      for (int e = 0; e < 8; ++e) T[r][cc + e] = (float)p0[e] + (float)p1[e];
    }
    __syncthreads();
#pragma unroll
    for (int p = 0; p < 2; ++p) {
      const int d = p * 32 + rr;
      const float bias_v = bv[c0 + d];
      h8v o;
#pragma unroll
      for (int e = 0; e < 8; ++e) o[e] = (h16)(T[cc + e][d] + bias_v);
      *(h8v*)(Vt + ((long)(b * 256 + c0 + d)) * 2048 + n0 + cc) = o;
    }
  }
}

// ---------------- scores GEMM + in-loop mask prefetch ------------------------------
// R6's terminal-epilogue mask read convoyed (all co-resident blocks hit it together
// -> 1.75 TB/s, 68 us). Now each of the 8 K-iters loads 1/8 of the 128x128 adj/dis
// tile as DENSE f4v/i4v alongside the A/B staging (shares the vmcnt drain), folds to
// h16 bias (adj>0 ? -dis : -30000) in a 36 KB LDS tile. Row stride 144 h16 (288 B =
// 72 words, %32 = 8) puts the epilogue's 4 row-groups on disjoint bank octets.
// LDS 8+8+36 = 52 KB -> still 3 blocks/CU.
#define MBS 144
__global__ __launch_bounds__(256) void scores_gemm_kernel(
    const h16* __restrict__ Q, const h16* __restrict__ Km,
    const float* __restrict__ dis, const int* __restrict__ adj,
    h16* __restrict__ Sh)
{
  __shared__ __align__(16) h16 As[4096];
  __shared__ __align__(16) h16 Bs[4096];
  __shared__ __align__(16) h16 Mb[128 * MBS];
  const int nt = blockIdx.x, mt = blockIdx.y, b = blockIdx.z;
  const int tid = threadIdx.x, lane = tid & 63, wv = tid >> 6;

  const h16* Abase = Q + ((long)b * NNODE + nt * 128) * 256;
  const h16* Bbase = Km + ((long)b * NNODE + mt * 128) * 256;

  const int srow = tid >> 2;
  const int sch  = ((tid & 3) ^ ((tid >> 3) & 3)) * 8;
  const h16* gA0 = Abase + (long)srow * 256 + sch;
  const h16* gA1 = Abase + (long)(srow + 64) * 256 + sch;
  const h16* gB0 = Bbase + (long)srow * 256 + sch;
  const h16* gB1 = Bbase + (long)(srow + 64) * 256 + sch;
  h16* lA0 = As + tid * 8;
  h16* lA1 = As + 2048 + tid * 8;
  h16* lB0 = Bs + tid * 8;
  h16* lB1 = Bs + 2048 + tid * 8;
  const int swz = ((lane & 15) >> 1) & 3;
  const int qq  = ((lane >> 4) ^ swz) * 8;
  const int amr = ((wv & 1) * 64 + (lane & 15)) * 32 + qq;
  const int bnr = ((wv >> 1) * 64 + (lane & 15)) * 32 + qq;

  const long gbase = (long)b * NNODE * NNODE + (long)(nt * 128) * 2048 + mt * 128;
  f4v acc[4][4];
  zero_acc(acc);

#pragma unroll 1
  for (int kt = 0; kt < 8; ++kt) {
    // mask slice kt: rows kt*16..+15 of the tile, two dense 4-elem chunks per thread
    const int f0 = kt * 2048 + tid * 4;          // elems 0..1023 -> rows +0..7
    const int f1 = f0 + 1024;                    // rows +8..15
    const int r0 = f0 >> 7, c0 = f0 & 127;
    const int r1 = f1 >> 7, c1 = f1 & 127;
    const long g0 = gbase + (long)r0 * 2048 + c0;
    const long g1 = gbase + (long)r1 * 2048 + c1;
    __syncthreads();
    f4v dv0 = *(const f4v*)(dis + g0);
    f4v dv1 = *(const f4v*)(dis + g1);
    i4v av0 = *(const i4v*)(adj + g0);
    i4v av1 = *(const i4v*)(adj + g1);
    const int k0 = kt * 32;
    async16(gA0 + k0, lA0);
    async16(gA1 + k0, lA1);
    async16(gB0 + k0, lB0);
    async16(gB1 + k0, lB1);
    asm volatile("s_waitcnt vmcnt(0)" ::: "memory");
    h4v m0, m1;
#pragma unroll
    for (int k = 0; k < 4; ++k) {
      m0[k] = (av0[k] > 0) ? (h16)(-dv0[k]) : (h16)(-30000.0f);
      m1[k] = (av1[k] > 0) ? (h16)(-dv1[k]) : (h16)(-30000.0f);
    }
    *(h4v*)(Mb + r0 * MBS + c0) = m0;
    *(h4v*)(Mb + r1 * MBS + c1) = m1;
    __syncthreads();
    h8v af[4], bf[4];
#pragma unroll
    for (int i = 0; i < 4; ++i) af[i] = *(const h8v*)(As + amr + i * 512);
#pragma unroll
    for (int j = 0; j < 4; ++j) bf[j] = *(const h8v*)(Bs + bnr + j * 512);
#pragma unroll
    for (int i = 0; i < 4; ++i)
#pragma unroll
      for (int j = 0; j < 4; ++j)
        acc[i][j] = MFMA16(af[i], bf[j], acc[i][j], 0, 0, 0);
  }
  // all Mb writes are older than kt=7's mid-loop sync -> safe to read without another

  const int rbase = (wv & 1) * 64 + (lane >> 4) * 4;
  const int cbase = (wv >> 1) * 64 + (lane & 15);
#pragma unroll
  for (int i = 0; i < 4; ++i) {
#pragma unroll
    for (int e = 0; e < 4; ++e) {
      const int row = rbase + i * 16 + e;
      const long ro = gbase + (long)row * 2048;
#pragma unroll
      for (int j = 0; j < 4; ++j) {
        const int col = cbase + j * 16;
        const float sv = acc[i][j][e] * 0.0625f + (float)Mb[row * MBS + col];
        Sh[ro + col] = (h16)sv;
      }
    }
  }
}

// ---------------- fused softmax + x_lst_new + attn (mask pre-applied) -------------
__global__ __launch_bounds__(256) void softmax_kernel(
    h16* __restrict__ Sh, const float* __restrict__ x_lst, float* __restrict__ out_x)
{
  const int r = blockIdx.x;                 // 0..8191 (b*2048+n)
  const long ro = (long)r * 2048;
  const int tid = threadIdx.x, lane = tid & 63, wv = tid >> 6;
  const int j0 = tid * 4;
  __shared__ float wmax[4], wsum[4];

  h4v sv0 = *(const h4v*)(Sh + ro + j0);
  h4v sv1 = *(const h4v*)(Sh + ro + 1024 + j0);

  float s[8];
#pragma unroll
  for (int k = 0; k < 4; ++k) { s[k] = (float)sv0[k]; s[k + 4] = (float)sv1[k]; }

  float m = s[0];
#pragma unroll
  for (int k = 1; k < 8; ++k) m = fmaxf(m, s[k]);
#pragma unroll
  for (int off = 32; off > 0; off >>= 1) m = fmaxf(m, __shfl_xor(m, off, 64));
  if (lane == 0) wmax[wv] = m;
  __syncthreads();
  m = fmaxf(fmaxf(wmax[0], wmax[1]), fmaxf(wmax[2], wmax[3]));

  float p[8], ls = 0.f;
#pragma unroll
  for (int k = 0; k < 8; ++k) { p[k] = __expf(s[k] - m); ls += p[k]; }
#pragma unroll
  for (int off = 32; off > 0; off >>= 1) ls += __shfl_xor(ls, off, 64);
  if (lane == 0) wsum[wv] = ls;
  __syncthreads();
  const float inv = 1.0f / (wsum[0] + wsum[1] + wsum[2] + wsum[3]);

  f4v x0 = *(const f4v*)(x_lst + ro + j0);
  f4v x1 = *(const f4v*)(x_lst + ro + 1024 + j0);
  f4v o0, o1;
  h4v pv0, pv1;
#pragma unroll
  for (int k = 0; k < 4; ++k) {
    const float a = p[k] * inv, bq = p[k + 4] * inv;
    o0[k] = x0[k] + a; o1[k] = x1[k] + bq;
    pv0[k] = (h16)a; pv1[k] = (h16)bq;
  }
  *(f4v*)(out_x + ro + j0) = o0;
  *(f4v*)(out_x + ro + 1024 + j0) = o1;
  *(h4v*)(Sh + ro + j0) = pv0;
  *(h4v*)(Sh + ro + 1024 + j0) = pv1;
}

// ---------------- AV GEMM (split-K x2): X1p[ks][m][d] f16 partials ----------------
__global__ __launch_bounds__(256) void av_gemm_kernel(
    const h16* __restrict__ Attn, const h16* __restrict__ Vt, h16* __restrict__ X1p)
{
  __shared__ __align__(16) h16 As[4096];
  __shared__ __align__(16) h16 Bs[4096];
  const int nt = blockIdx.x, b = blockIdx.z;
  const int ct = blockIdx.y & 1, ks = blockIdx.y >> 1;
  const h16* Abase = Attn + ((long)b * NNODE + nt * 128) * 2048 + ks * 1024;
  const h16* Bbase = Vt + ((long)b * 256 + ct * 128) * 2048 + ks * 1024;
  f4v acc[4][4];
  zero_acc(acc);
  gemm_tile(Abase, 2048, Bbase, 2048, As, Bs, acc, 32);

  const int lane = threadIdx.x & 63, wv = threadIdx.x >> 6;
  const int rbase = (wv & 1) * 64 + (lane >> 4) * 4;
  const int cbase = (wv >> 1) * 64 + (lane & 15);
  h16* dst = X1p + (long)ks * PARTN;
#pragma unroll
  for (int i = 0; i < 4; ++i) {
#pragma unroll
    for (int e = 0; e < 4; ++e) {
      const long row = (long)b * NNODE + nt * 128 + rbase + i * 16 + e;
#pragma unroll
      for (int j = 0; j < 4; ++j) {
        const int col = ct * 128 + cbase + j * 16;
        dst[row * 256 + col] = (h16)acc[i][j][e];
      }
    }
  }
}

// ---------------- fused residual + partial-sum + LayerNorm1 -----------------------
__device__ __forceinline__ float wred_sum(float v) {
#pragma unroll
  for (int off = 32; off > 0; off >>= 1) v += __shfl_xor(v, off, 64);
  return v;
}

__global__ __launch_bounds__(256) void ln1_kernel(
    const float* __restrict__ X, const h16* __restrict__ Y, const h16* __restrict__ Y2,
    const float* __restrict__ g, const float* __restrict__ bb,
    float* __restrict__ outF, h16* __restrict__ outH)
{
  const int wv = threadIdx.x >> 6, lane = threadIdx.x & 63;
  const long r = (long)blockIdx.x * 4 + wv;
  const long off = r * 256 + lane * 4;
  f4v x = *(const f4v*)(X + off);
  h4v y = *(const h4v*)(Y + off);
  h4v y2 = *(const h4v*)(Y2 + off);
  float v[4];
  float sum = 0.f, sq = 0.f;
#pragma unroll
  for (int k = 0; k < 4; ++k) {
    v[k] = x[k] + (float)y[k] + (float)y2[k];
    sum += v[k]; sq += v[k] * v[k];
  }
  sum = wred_sum(sum);
  sq  = wred_sum(sq);
  const float mu = sum * (1.0f / 256.0f);
  const float var = sq * (1.0f / 256.0f) - mu * mu;
  const float rs = rsqrtf(var + 1e-5f);
  f4v gg = *(const f4v*)(g + lane * 4);
  f4v be = *(const f4v*)(bb + lane * 4);
  f4v o;
#pragma unroll
  for (int k = 0; k < 4; ++k) o[k] = (v[k] - mu) * rs * gg[k] + be[k];
  *(f4v*)(outF + off) = o;
  h4v hv;
#pragma unroll
  for (int k = 0; k < 4; ++k) hv[k] = (h16)o[k];
  *(h4v*)(outH + off) = hv;
}

// ---------------- fused 3-layer MLP + residual + LayerNorm2 -----------------------
__global__ __launch_bounds__(256) void mlp_fused_kernel(
    const h16* __restrict__ H16, const float* __restrict__ Hf,
    const h16* __restrict__ Wl,
    const float* __restrict__ b1, const float* __restrict__ b2, const float* __restrict__ b3,
    const float* __restrict__ g2, const float* __restrict__ be2,
    float* __restrict__ out_h)
{
  __shared__ h16 Xa[32][264];
  __shared__ h16 Xb[32][264];
  __shared__ __align__(16) h16 Bs[8192];      // 256 out-cols x 32 k
  const int tid = threadIdx.x, lane = tid & 63, wv = tid >> 6;
  const int m0 = blockIdx.x * 32;

  { // load LN1 output rows into Xa (coalesced global, padded LDS writes)
    const int r = tid >> 3, cq = (tid & 7) * 32;
    const h16* s = H16 + (long)(m0 + r) * 256 + cq;
#pragma unroll
    for (int k = 0; k < 4; ++k)
      *(h8v*)&Xa[r][cq + k * 8] = *(const h8v*)(s + k * 8);
  }

  const int srow = tid >> 2;
  const int sch  = ((tid & 3) ^ ((tid >> 3) & 3)) * 8;
  h16* lB = Bs + tid * 8;
  const int quad = lane >> 4;
  const float* biases[3] = {b1, b2, b3};

  for (int layer = 0; layer < 3; ++layer) {
    const h16* W = Wl + layer * 65536;
    const h16 (*Xi)[264] = (layer == 1) ? (const h16(*)[264])Xb : (const h16(*)[264])Xa;
    h16 (*Xo)[264] = (layer == 1) ? Xa : Xb;
    f4v acc[2][4];
#pragma unroll
    for (int i = 0; i < 2; ++i)
#pragma unroll
      for (int j = 0; j < 4; ++j) { f4v z = {0.f,0.f,0.f,0.f}; acc[i][j] = z; }

    for (int kt = 0; kt < 8; ++kt) {
      __syncthreads();
      const h16* gB = W + (long)srow * 256 + kt * 32 + sch;
      async16(gB, lB);
      async16(gB + 64 * 256, lB + 64 * 32);
      async16(gB + 128 * 256, lB + 128 * 32);
      async16(gB + 192 * 256, lB + 192 * 32);
      asm volatile("s_waitcnt vmcnt(0)" ::: "memory");
      __syncthreads();
      h8v af[2], bf[4];
#pragma unroll
      for (int i = 0; i < 2; ++i)
        af[i] = *(const h8v*)&Xi[i * 16 + (lane & 15)][kt * 32 + quad * 8];
#pragma unroll
      for (int j = 0; j < 4; ++j) {
        const int n = wv * 64 + j * 16 + (lane & 15);
        const int q = (quad ^ ((n >> 1) & 3)) * 8;
        bf[j] = *(const h8v*)(Bs + n * 32 + q);
      }
#pragma unroll
      for (int i = 0; i < 2; ++i)
#pragma unroll
        for (int j = 0; j < 4; ++j)
          acc[i][j] = MFMA16(af[i], bf[j], acc[i][j], 0, 0, 0);
    }
    // epilogue: bias (+leaky for layers 0/1), write to Xo (other buffer -> no race)
    const int rb = quad * 4;
    const int cb = wv * 64 + (lane & 15);
    const float* bias = biases[layer];
    const bool leaky = (layer < 2);
#pragma unroll
    for (int j = 0; j < 4; ++j) {
      const int col = cb + j * 16;
      const float bv = bias[col];
#pragma unroll
      for (int i = 0; i < 2; ++i)
#pragma unroll
        for (int e = 0; e < 4; ++e) {
          float v = acc[i][j][e] + bv;
          if (leaky) v = (v >= 0.f) ? v : 0.01f * v;
          Xo[i * 16 + rb + e][col] = (h16)v;
        }
    }
  }
  __syncthreads();

  // LN2: rows in Xb (layer-3 out), residual Hf, write out_h. 8 threads/row.
  const int r = tid >> 3, c0 = (tid & 7) * 32;
  const float* hrow = Hf + (long)(m0 + r) * 256 + c0;
  float v[32];
  float s = 0.f, sq = 0.f;
#pragma unroll
  for (int k8 = 0; k8 < 8; ++k8) {
    f4v h4 = *(const f4v*)(hrow + k8 * 4);
#pragma unroll
    for (int e = 0; e < 4; ++e) {
      float t = (float)Xb[r][c0 + k8 * 4 + e] + h4[e];
      v[k8 * 4 + e] = t; s += t; sq += t * t;
    }
  }
#pragma unroll
  for (int off = 1; off < 8; off <<= 1) { s += __shfl_xor(s, off, 64); sq += __shfl_xor(sq, off, 64); }
  const float mu = s * (1.0f / 256.0f);
  const float var = sq * (1.0f / 256.0f) - mu * mu;
  const float rs = rsqrtf(var + 1e-5f);
  float* orow = out_h + (long)(m0 + r) * 256 + c0;
#pragma unroll
  for (int k8 = 0; k8 < 8; ++k8) {
    f4v gg = *(const f4v*)(g2 + c0 + k8 * 4);
    f4v be = *(const f4v*)(be2 + c0 + k8 * 4);
    f4v o;
#pragma unroll
    for (int e = 0; e < 4; ++e) o[e] = (v[k8 * 4 + e] - mu) * rs * gg[e] + be[e];
    *(f4v*)(orow + k8 * 4) = o;
  }
}

// ---------------- launch ----------------------------------------------------------
extern "C" void kernel_launch(void* const* d_in, const int* in_sizes, int n_in,
                              void* d_out, int out_size, void* d_ws, size_t ws_size,
                              hipStream_t stream)
{
  const float* src  = (const float*)d_in[0];
  const float* xlst = (const float*)d_in[1];
  const int*   adj  = (const int*)d_in[2];
  const float* dis  = (const float*)d_in[3];
  const float* Wq   = (const float*)d_in[4];
  const float* bq   = (const float*)d_in[5];
  const float* Wk   = (const float*)d_in[6];
  const float* bk   = (const float*)d_in[7];
  const float* Wv   = (const float*)d_in[8];
  const float* bvp  = (const float*)d_in[9];
  const float* W1   = (const float*)d_in[10];
  const float* b1   = (const float*)d_in[11];
  const float* W2   = (const float*)d_in[12];
  const float* b2   = (const float*)d_in[13];
  const float* W3   = (const float*)d_in[14];
  const float* b3   = (const float*)d_in[15];
  const float* g1   = (const float*)d_in[16];
  const float* be1  = (const float*)d_in[17];
  const float* g2   = (const float*)d_in[18];
  const float* be2  = (const float*)d_in[19];
  (void)in_sizes; (void)n_in; (void)out_size; (void)ws_size;

  char* ws = (char*)d_ws;
  size_t off = 0;
  auto alloc = [&](size_t bytes) -> void* {
    void* p = ws + off;
    off += (bytes + 1023) & ~(size_t)1023;
    return p;
  };
  h16*   Xpad = (h16*)  alloc((size_t)NBATCH * NPAD * DM * 2);       // 4.2 MB
  h16*   Wt   = (h16*)  alloc((size_t)3 * 256 * 4096 * 2);           // 6.3 MB
  h16*   Wl   = (h16*)  alloc((size_t)3 * 256 * 256 * 2);            // 0.4 MB
  h16*   Qb   = (h16*)  alloc((size_t)QKELEM * 2);                   // 4 MB
  h16*   Kb   = (h16*)  alloc((size_t)QKELEM * 2);                   // 4 MB
  h16*   Vt   = (h16*)  alloc((size_t)QKELEM * 2);                   // 4 MB
  // union region R: conv partials (25 MB, dead after reduce) overlap Sh/X1p.
  char*  R    = (char*) alloc((size_t)66000 * 1024);                 // ~64.5 MB
  h16*   Qp   = (h16*)R;                                   // [2][m][c]  8.4 MB
  h16*   Kp   = (h16*)(R + (size_t)2 * QKELEM * 2);        // [2][m][c]  8.4 MB
  h16*   Vp   = (h16*)(R + (size_t)4 * QKELEM * 2);        // [2][m][c]  8.4 MB
  h16*   Sh   = (h16*)R;                                   // 32 MB (over dead Qp/Kp/Vp)
  h16*   X1p  = (h16*)(R + (size_t)8 * QKELEM * 2);        // 8.4 MB (just past Sh)
  float* H    = (float*)(R + (size_t)12 * QKELEM * 2);     // 8 MB
  h16*   H16  = (h16*)((char*)H + (size_t)PARTN * 4);      // 4 MB

  float* out_h = (float*)d_out;                        // [B,N,d]
  float* out_x = out_h + (size_t)NBATCH * NNODE * DM;  // [B,N,N]

  prep_all_kernel<<<NSRC_BLK + 768 + 768, 256, 0, stream>>>(
      src, Wq, Wk, Wv, W1, W2, W3, Xpad, Wt, Wl);
  conv_gemm256_kernel<<<dim3(32, 3, 2), 512, 0, stream>>>(Xpad, Wt, Qp, Kp, Vp);
  conv_reduce_kernel<<<2048 + 512, 256, 0, stream>>>(
      Qp, Kp, Vp, bq, bk, bvp, Qb, Kb, Vt);
  scores_gemm_kernel<<<dim3(16, 16, 4), 256, 0, stream>>>(Qb, Kb, dis, adj, Sh);
  softmax_kernel<<<NBATCH * NNODE, 256, 0, stream>>>(Sh, xlst, out_x);
  av_gemm_kernel<<<dim3(16, 4, 4), 256, 0, stream>>>(Sh, Vt, X1p);
  ln1_kernel<<<(NBATCH * NNODE) / 4, 256, 0, stream>>>(src, X1p, X1p + PARTN, g1, be1, H, H16);
  mlp_fused_kernel<<<NBATCH * NNODE / 32, 256, 0, stream>>>(
      H16, H, Wl, b1, b2, b3, g2, be2, out_h);
}